// Round 1
// baseline (1960.208 us; speedup 1.0000x reference)
//
#include <hip/hip_runtime.h>

#define N_NODES 100000
#define N_EDGES 1200000
#define N_FEAT 128
#define HIDDEN 64
#define N_CLASSES 40

// ---------------- degree / normalization ----------------

__global__ void init_deg_kernel(float* deg, int n) {
    int i = blockIdx.x * blockDim.x + threadIdx.x;
    if (i < n) deg[i] = 1.0f;  // self loop contributes 1
}

__global__ void accum_deg_kernel(const int* __restrict__ col, float* deg, int e) {
    int i = blockIdx.x * blockDim.x + threadIdx.x;
    if (i < e) unsafeAtomicAdd(&deg[col[i]], 1.0f);
}

__global__ void rsqrt_kernel(float* deg, int n) {
    int i = blockIdx.x * blockDim.x + threadIdx.x;
    if (i < n) deg[i] = rsqrtf(deg[i]);
}

// ---------------- tiled GEMM: H[M,NOUT] = X[M,K] @ W[K,NOUT] ----------------
// Block tile: 64 nodes x NOUT features. Thread tile: 4 nodes x 4 features.
// X tile staged k-major (transposed) in LDS, W staged as-is.

template <int K, int NOUT>
__global__ __launch_bounds__(256) void gemm_kernel(const float* __restrict__ X,
                                                   const float* __restrict__ W,
                                                   float* __restrict__ H, int M) {
    constexpr int TI = 16;          // node-dimension threads (4 nodes each)
    constexpr int TJ = NOUT / 4;    // feature-dimension threads (4 feats each)
    constexpr int BN = 64;          // nodes per block
    constexpr int XPITCH = BN + 4;  // 68: keeps float4 alignment, 2-way max conflict

    __shared__ float ws[K * NOUT];
    __shared__ float xs[K * XPITCH];

    const int tid = threadIdx.x;
    const int node0 = blockIdx.x * BN;

    // stage W
    for (int i = tid; i < K * NOUT; i += 256) ws[i] = W[i];

    // stage X tile, transposed to xs[k][node]
    constexpr int NF4 = BN * (K / 4);
    for (int idx = tid; idx < NF4; idx += 256) {
        int node = idx / (K / 4);
        int k4 = idx % (K / 4);
        float4 v = make_float4(0.f, 0.f, 0.f, 0.f);
        if (node0 + node < M) v = *(const float4*)&X[(size_t)(node0 + node) * K + k4 * 4];
        xs[(k4 * 4 + 0) * XPITCH + node] = v.x;
        xs[(k4 * 4 + 1) * XPITCH + node] = v.y;
        xs[(k4 * 4 + 2) * XPITCH + node] = v.z;
        xs[(k4 * 4 + 3) * XPITCH + node] = v.w;
    }
    __syncthreads();

    if (tid < TI * TJ) {
        const int ti = tid % TI;
        const int tj = tid / TI;
        float acc[4][4];
#pragma unroll
        for (int a = 0; a < 4; ++a)
#pragma unroll
            for (int b = 0; b < 4; ++b) acc[a][b] = 0.f;

        for (int k = 0; k < K; ++k) {
            float4 xv = *(const float4*)&xs[k * XPITCH + ti * 4];
            float4 wv = *(const float4*)&ws[k * NOUT + tj * 4];
            const float xa[4] = {xv.x, xv.y, xv.z, xv.w};
            const float wb[4] = {wv.x, wv.y, wv.z, wv.w};
#pragma unroll
            for (int a = 0; a < 4; ++a)
#pragma unroll
                for (int b = 0; b < 4; ++b) acc[a][b] = fmaf(xa[a], wb[b], acc[a][b]);
        }

#pragma unroll
        for (int a = 0; a < 4; ++a) {
            int node = node0 + ti * 4 + a;
            if (node < M) {
                float4 o = make_float4(acc[a][0], acc[a][1], acc[a][2], acc[a][3]);
                *(float4*)&H[(size_t)node * NOUT + tj * 4] = o;
            }
        }
    }
}

// ---------------- edge scatter: out[col] += h[row] * dinv[row]*dinv[col] ----------------

template <int F>
__global__ void scatter_kernel(const int* __restrict__ row, const int* __restrict__ col,
                               const float* __restrict__ dinv, const float* __restrict__ h,
                               float* __restrict__ out, int E) {
    constexpr int F4 = F / 4;
    long long t = (long long)blockIdx.x * blockDim.x + threadIdx.x;
    if (t >= (long long)E * F4) return;
    int e = (int)(t / F4);
    int f = (int)(t % F4);
    int r = row[e];
    int c = col[e];
    float nrm = dinv[r] * dinv[c];
    float4 v = *(const float4*)&h[(size_t)r * F + f * 4];
    float* o = &out[(size_t)c * F + f * 4];
    unsafeAtomicAdd(o + 0, v.x * nrm);
    unsafeAtomicAdd(o + 1, v.y * nrm);
    unsafeAtomicAdd(o + 2, v.z * nrm);
    unsafeAtomicAdd(o + 3, v.w * nrm);
}

// ---------------- epilogues ----------------

// agg1 = relu(agg1 + h1 * dinv^2 + b1)   (self loop + bias + relu)
__global__ void epi1_kernel(float* __restrict__ agg, const float* __restrict__ h,
                            const float* __restrict__ dinv, const float* __restrict__ b, int n) {
    int i = blockIdx.x * blockDim.x + threadIdx.x;
    if (i < n) {
        int node = i >> 6;  // /64
        int j = i & 63;
        float di = dinv[node];
        float v = agg[i] + h[i] * di * di + b[j];
        agg[i] = fmaxf(v, 0.f);
    }
}

// out = h2 * dinv^2 + b2   (init output with self loop + bias; edge atomics add on top)
__global__ void init_out_kernel(float* __restrict__ out, const float* __restrict__ h,
                                const float* __restrict__ dinv, const float* __restrict__ b,
                                int n) {
    int i = blockIdx.x * blockDim.x + threadIdx.x;
    if (i < n) {
        int node = i / N_CLASSES;
        int j = i - node * N_CLASSES;
        float di = dinv[node];
        out[i] = h[i] * di * di + b[j];
    }
}

// ---------------- launch ----------------

extern "C" void kernel_launch(void* const* d_in, const int* in_sizes, int n_in,
                              void* d_out, int out_size, void* d_ws, size_t ws_size,
                              hipStream_t stream) {
    const float* x = (const float*)d_in[0];
    const int* row = (const int*)d_in[1];           // edge_index[0], E entries
    const int* col = row + N_EDGES;                 // edge_index[1]
    const float* W1 = (const float*)d_in[2];
    const float* b1 = (const float*)d_in[3];
    const float* W2 = (const float*)d_in[4];
    const float* b2 = (const float*)d_in[5];
    float* out = (float*)d_out;

    float* ws = (float*)d_ws;
    float* dinv = ws;                                // N
    float* h1 = dinv + N_NODES;                      // N*64
    float* agg1 = h1 + (size_t)N_NODES * HIDDEN;     // N*64
    float* h2 = agg1 + (size_t)N_NODES * HIDDEN;     // N*40

    const int N = N_NODES, E = N_EDGES;

    init_deg_kernel<<<(N + 255) / 256, 256, 0, stream>>>(dinv, N);
    accum_deg_kernel<<<(E + 255) / 256, 256, 0, stream>>>(col, dinv, E);
    rsqrt_kernel<<<(N + 255) / 256, 256, 0, stream>>>(dinv, N);

    // layer 1: transform
    gemm_kernel<N_FEAT, HIDDEN><<<(N + 63) / 64, 256, 0, stream>>>(x, W1, h1, N);

    // layer 1: aggregate
    hipMemsetAsync(agg1, 0, (size_t)N * HIDDEN * sizeof(float), stream);
    {
        long long work = (long long)E * (HIDDEN / 4);
        scatter_kernel<HIDDEN><<<(int)((work + 255) / 256), 256, 0, stream>>>(
            row, col, dinv, h1, agg1, E);
    }
    epi1_kernel<<<(N * HIDDEN + 255) / 256, 256, 0, stream>>>(agg1, h1, dinv, b1, N * HIDDEN);

    // layer 2: transform
    gemm_kernel<HIDDEN, N_CLASSES><<<(N + 63) / 64, 256, 0, stream>>>(agg1, W2, h2, N);

    // layer 2: aggregate into d_out
    init_out_kernel<<<(N * N_CLASSES + 255) / 256, 256, 0, stream>>>(out, h2, dinv, b2,
                                                                     N * N_CLASSES);
    {
        long long work = (long long)E * (N_CLASSES / 4);
        scatter_kernel<N_CLASSES><<<(int)((work + 255) / 256), 256, 0, stream>>>(
            row, col, dinv, h2, out, E);
    }
}

// Round 2
// 683.382 us; speedup vs baseline: 2.8684x; 2.8684x over previous
//
#include <hip/hip_runtime.h>

#define N_NODES 100000
#define N_EDGES 1200000
#define N_FEAT 128
#define HIDDEN 64
#define N_CLASSES 40

// ---------------- CSR build ----------------

__global__ void hist_kernel(const int* __restrict__ col, int* __restrict__ cnt, int e) {
    int i = blockIdx.x * blockDim.x + threadIdx.x;
    if (i < e) atomicAdd(&cnt[col[i]], 1);
}

__global__ void dinv_kernel(const int* __restrict__ cnt, float* __restrict__ dinv, int n) {
    int i = blockIdx.x * blockDim.x + threadIdx.x;
    if (i < n) dinv[i] = rsqrtf((float)(cnt[i] + 1));  // +1 self loop
}

// single-block exclusive scan of cnt[0..n) -> rowptr[0..n]; also copies to cursor
__global__ __launch_bounds__(256) void scan_kernel(const int* __restrict__ cnt,
                                                   int* __restrict__ rowptr,
                                                   int* __restrict__ cursor, int n) {
    __shared__ int sums[256];
    const int tid = threadIdx.x;
    const int per = (n + 255) / 256;
    const int start = tid * per;
    const int end = min(start + per, n);

    int local = 0;
    for (int i = start; i < end; ++i) local += cnt[i];
    sums[tid] = local;
    __syncthreads();

    for (int d = 1; d < 256; d <<= 1) {
        int add = (tid >= d) ? sums[tid - d] : 0;
        __syncthreads();
        sums[tid] += add;
        __syncthreads();
    }
    int off = (tid == 0) ? 0 : sums[tid - 1];

    for (int i = start; i < end; ++i) {
        rowptr[i] = off;
        cursor[i] = off;
        off += cnt[i];
    }
    if (end == n) rowptr[n] = off;
}

__global__ void fill_kernel(const int* __restrict__ row, const int* __restrict__ col,
                            int* __restrict__ cursor, int* __restrict__ csr_src, int e) {
    int i = blockIdx.x * blockDim.x + threadIdx.x;
    if (i < e) {
        int c = col[i];
        int pos = atomicAdd(&cursor[c], 1);
        csr_src[pos] = row[i];
    }
}

// ---------------- tiled GEMM: H[M,NOUT] = X[M,K] @ W[K,NOUT] ----------------

template <int K, int NOUT>
__global__ __launch_bounds__(256) void gemm_kernel(const float* __restrict__ X,
                                                   const float* __restrict__ W,
                                                   float* __restrict__ H, int M) {
    constexpr int TI = 16;
    constexpr int TJ = NOUT / 4;
    constexpr int BN = 64;
    constexpr int XPITCH = BN + 4;

    __shared__ float ws[K * NOUT];
    __shared__ float xs[K * XPITCH];

    const int tid = threadIdx.x;
    const int node0 = blockIdx.x * BN;

    for (int i = tid; i < K * NOUT; i += 256) ws[i] = W[i];

    constexpr int NF4 = BN * (K / 4);
    for (int idx = tid; idx < NF4; idx += 256) {
        int node = idx / (K / 4);
        int k4 = idx % (K / 4);
        float4 v = make_float4(0.f, 0.f, 0.f, 0.f);
        if (node0 + node < M) v = *(const float4*)&X[(size_t)(node0 + node) * K + k4 * 4];
        xs[(k4 * 4 + 0) * XPITCH + node] = v.x;
        xs[(k4 * 4 + 1) * XPITCH + node] = v.y;
        xs[(k4 * 4 + 2) * XPITCH + node] = v.z;
        xs[(k4 * 4 + 3) * XPITCH + node] = v.w;
    }
    __syncthreads();

    if (tid < TI * TJ) {
        const int ti = tid % TI;
        const int tj = tid / TI;
        float acc[4][4];
#pragma unroll
        for (int a = 0; a < 4; ++a)
#pragma unroll
            for (int b = 0; b < 4; ++b) acc[a][b] = 0.f;

        for (int k = 0; k < K; ++k) {
            float4 xv = *(const float4*)&xs[k * XPITCH + ti * 4];
            float4 wv = *(const float4*)&ws[k * NOUT + tj * 4];
            const float xa[4] = {xv.x, xv.y, xv.z, xv.w};
            const float wb[4] = {wv.x, wv.y, wv.z, wv.w};
#pragma unroll
            for (int a = 0; a < 4; ++a)
#pragma unroll
                for (int b = 0; b < 4; ++b) acc[a][b] = fmaf(xa[a], wb[b], acc[a][b]);
        }

#pragma unroll
        for (int a = 0; a < 4; ++a) {
            int node = node0 + ti * 4 + a;
            if (node < M) {
                float4 o = make_float4(acc[a][0], acc[a][1], acc[a][2], acc[a][3]);
                *(float4*)&H[(size_t)node * NOUT + tj * 4] = o;
            }
        }
    }
}

// ---------------- per-node wave gather ----------------
// One 64-lane wave per destination node c:
//   out[c,f] = (relu?) ( sum_{e in in(c)} h[src,f]*dinv[src]*dinv[c]
//                        + h[c,f]*dinv[c]^2 + b[f] )

template <int F, bool RELU>
__global__ __launch_bounds__(256) void gather_kernel(const int* __restrict__ rowptr,
                                                     const int* __restrict__ csr_src,
                                                     const float* __restrict__ dinv,
                                                     const float* __restrict__ h,
                                                     const float* __restrict__ b,
                                                     float* __restrict__ out, int n) {
    const int wave = (blockIdx.x * blockDim.x + threadIdx.x) >> 6;
    const int lane = threadIdx.x & 63;
    if (wave >= n) return;
    const int c = wave;
    const float dc = dinv[c];

    float acc = 0.f;
    if (lane < F) acc = h[(size_t)c * F + lane] * dc * dc + b[lane];

    int e = rowptr[c];
    const int eEnd = rowptr[c + 1];
    for (; e + 1 < eEnd; e += 2) {
        int r0 = csr_src[e];
        int r1 = csr_src[e + 1];
        float n0 = dinv[r0] * dc;
        float n1 = dinv[r1] * dc;
        if (lane < F) {
            float v0 = h[(size_t)r0 * F + lane];
            float v1 = h[(size_t)r1 * F + lane];
            acc = fmaf(v0, n0, acc);
            acc = fmaf(v1, n1, acc);
        }
    }
    if (e < eEnd) {
        int r0 = csr_src[e];
        float n0 = dinv[r0] * dc;
        if (lane < F) acc = fmaf(h[(size_t)r0 * F + lane], n0, acc);
    }

    if (lane < F) out[(size_t)c * F + lane] = RELU ? fmaxf(acc, 0.f) : acc;
}

// ---------------- launch ----------------

extern "C" void kernel_launch(void* const* d_in, const int* in_sizes, int n_in,
                              void* d_out, int out_size, void* d_ws, size_t ws_size,
                              hipStream_t stream) {
    const float* x = (const float*)d_in[0];
    const int* row = (const int*)d_in[1];
    const int* col = row + N_EDGES;
    const float* W1 = (const float*)d_in[2];
    const float* b1 = (const float*)d_in[3];
    const float* W2 = (const float*)d_in[4];
    const float* b2 = (const float*)d_in[5];
    float* out = (float*)d_out;

    const int N = N_NODES, E = N_EDGES;

    // workspace layout (16B-aligned chunks)
    char* p = (char*)d_ws;
    auto alloc = [&](size_t bytes) {
        char* q = p;
        p += (bytes + 15) & ~(size_t)15;
        return q;
    };
    int* cnt = (int*)alloc((size_t)N * 4);
    int* rowptr = (int*)alloc((size_t)(N + 1) * 4);
    int* cursor = (int*)alloc((size_t)N * 4);
    int* csr_src = (int*)alloc((size_t)E * 4);
    float* dinv = (float*)alloc((size_t)N * 4);
    float* h1 = (float*)alloc((size_t)N * HIDDEN * 4);
    float* agg1 = (float*)alloc((size_t)N * HIDDEN * 4);
    float* h2 = (float*)alloc((size_t)N * N_CLASSES * 4);

    // CSR build
    hipMemsetAsync(cnt, 0, (size_t)N * 4, stream);
    hist_kernel<<<(E + 255) / 256, 256, 0, stream>>>(col, cnt, E);
    dinv_kernel<<<(N + 255) / 256, 256, 0, stream>>>(cnt, dinv, N);
    scan_kernel<<<1, 256, 0, stream>>>(cnt, rowptr, cursor, N);
    fill_kernel<<<(E + 255) / 256, 256, 0, stream>>>(row, col, cursor, csr_src, E);

    // layer 1
    gemm_kernel<N_FEAT, HIDDEN><<<(N + 63) / 64, 256, 0, stream>>>(x, W1, h1, N);
    gather_kernel<HIDDEN, true><<<(N + 3) / 4, 256, 0, stream>>>(rowptr, csr_src, dinv, h1,
                                                                 b1, agg1, N);

    // layer 2
    gemm_kernel<HIDDEN, N_CLASSES><<<(N + 63) / 64, 256, 0, stream>>>(agg1, W2, h2, N);
    gather_kernel<N_CLASSES, false><<<(N + 3) / 4, 256, 0, stream>>>(rowptr, csr_src, dinv, h2,
                                                                     b2, out, N);
}

// Round 3
// 463.238 us; speedup vs baseline: 4.2315x; 1.4752x over previous
//
#include <hip/hip_runtime.h>

#define N_NODES 100000
#define N_EDGES 1200000
#define N_FEAT 128
#define HIDDEN 64
#define N_CLASSES 40

// ---------------- CSR build ----------------

__global__ void hist_kernel(const int* __restrict__ col, int* __restrict__ cnt, int e) {
    int i = blockIdx.x * blockDim.x + threadIdx.x;
    if (i < e) atomicAdd(&cnt[col[i]], 1);
}

__global__ void dinv_kernel(const int* __restrict__ cnt, float* __restrict__ dinv, int n) {
    int i = blockIdx.x * blockDim.x + threadIdx.x;
    if (i < n) dinv[i] = rsqrtf((float)(cnt[i] + 1));  // +1 self loop
}

// ---- hierarchical exclusive scan of cnt[0..n) -> rowptr/cursor ----
// phase 1: per-block (1024-elem chunk) sums
__global__ __launch_bounds__(256) void block_sum_kernel(const int* __restrict__ cnt,
                                                        int* __restrict__ blockSums, int n) {
    __shared__ int lds[256];
    const int b = blockIdx.x, t = threadIdx.x;
    const int base = b * 1024 + t * 4;
    int s = 0;
#pragma unroll
    for (int k = 0; k < 4; ++k) {
        int i = base + k;
        if (i < n) s += cnt[i];
    }
    lds[t] = s;
    __syncthreads();
    for (int d = 128; d > 0; d >>= 1) {
        if (t < d) lds[t] += lds[t + d];
        __syncthreads();
    }
    if (t == 0) blockSums[b] = lds[0];
}

// phase 2: single block exclusive scan of blockSums (nb <= 256)
__global__ __launch_bounds__(256) void scan_sums_kernel(int* __restrict__ blockSums, int nb) {
    __shared__ int lds[256];
    const int t = threadIdx.x;
    const int v = (t < nb) ? blockSums[t] : 0;
    lds[t] = v;
    __syncthreads();
    for (int d = 1; d < 256; d <<= 1) {
        int add = (t >= d) ? lds[t - d] : 0;
        __syncthreads();
        lds[t] += add;
        __syncthreads();
    }
    if (t < nb) blockSums[t] = lds[t] - v;  // exclusive
}

// phase 3: per-block local scan + block offset -> rowptr & cursor
__global__ __launch_bounds__(256) void scan_write_kernel(const int* __restrict__ cnt,
                                                         const int* __restrict__ blockSums,
                                                         int* __restrict__ rowptr,
                                                         int* __restrict__ cursor, int n) {
    __shared__ int lds[256];
    const int b = blockIdx.x, t = threadIdx.x;
    const int base = b * 1024 + t * 4;
    int v[4];
    int s = 0;
#pragma unroll
    for (int k = 0; k < 4; ++k) {
        int i = base + k;
        v[k] = (i < n) ? cnt[i] : 0;
        s += v[k];
    }
    lds[t] = s;
    __syncthreads();
    for (int d = 1; d < 256; d <<= 1) {
        int add = (t >= d) ? lds[t - d] : 0;
        __syncthreads();
        lds[t] += add;
        __syncthreads();
    }
    int off = blockSums[b] + lds[t] - s;  // exclusive prefix for this thread's 4 elems
#pragma unroll
    for (int k = 0; k < 4; ++k) {
        int i = base + k;
        if (i < n) {
            rowptr[i] = off;
            cursor[i] = off;
        }
        off += v[k];
    }
    if (b == 0 && t == 0) rowptr[n] = N_EDGES;
}

__global__ void fill_kernel(const int* __restrict__ row, const int* __restrict__ col,
                            int* __restrict__ cursor, int* __restrict__ csr_src, int e) {
    int i = blockIdx.x * blockDim.x + threadIdx.x;
    if (i < e) {
        int c = col[i];
        int pos = atomicAdd(&cursor[c], 1);
        csr_src[pos] = row[i];
    }
}

// ---------------- tiled GEMM: H[M,NOUT] = X[M,K] @ W[K,NOUT] ----------------

template <int K, int NOUT>
__global__ __launch_bounds__(256) void gemm_kernel(const float* __restrict__ X,
                                                   const float* __restrict__ W,
                                                   float* __restrict__ H, int M) {
    constexpr int TI = 16;
    constexpr int TJ = NOUT / 4;
    constexpr int BN = 64;
    constexpr int XPITCH = BN + 4;

    __shared__ float ws[K * NOUT];
    __shared__ float xs[K * XPITCH];

    const int tid = threadIdx.x;
    const int node0 = blockIdx.x * BN;

    for (int i = tid; i < K * NOUT; i += 256) ws[i] = W[i];

    constexpr int NF4 = BN * (K / 4);
    for (int idx = tid; idx < NF4; idx += 256) {
        int node = idx / (K / 4);
        int k4 = idx % (K / 4);
        float4 v = make_float4(0.f, 0.f, 0.f, 0.f);
        if (node0 + node < M) v = *(const float4*)&X[(size_t)(node0 + node) * K + k4 * 4];
        xs[(k4 * 4 + 0) * XPITCH + node] = v.x;
        xs[(k4 * 4 + 1) * XPITCH + node] = v.y;
        xs[(k4 * 4 + 2) * XPITCH + node] = v.z;
        xs[(k4 * 4 + 3) * XPITCH + node] = v.w;
    }
    __syncthreads();

    if (tid < TI * TJ) {
        const int ti = tid % TI;
        const int tj = tid / TI;
        float acc[4][4];
#pragma unroll
        for (int a = 0; a < 4; ++a)
#pragma unroll
            for (int b = 0; b < 4; ++b) acc[a][b] = 0.f;

        for (int k = 0; k < K; ++k) {
            float4 xv = *(const float4*)&xs[k * XPITCH + ti * 4];
            float4 wv = *(const float4*)&ws[k * NOUT + tj * 4];
            const float xa[4] = {xv.x, xv.y, xv.z, xv.w};
            const float wb[4] = {wv.x, wv.y, wv.z, wv.w};
#pragma unroll
            for (int a = 0; a < 4; ++a)
#pragma unroll
                for (int b = 0; b < 4; ++b) acc[a][b] = fmaf(xa[a], wb[b], acc[a][b]);
        }

#pragma unroll
        for (int a = 0; a < 4; ++a) {
            int node = node0 + ti * 4 + a;
            if (node < M) {
                float4 o = make_float4(acc[a][0], acc[a][1], acc[a][2], acc[a][3]);
                *(float4*)&H[(size_t)node * NOUT + tj * 4] = o;
            }
        }
    }
}

// ---------------- per-node wave gather ----------------

template <int F, bool RELU>
__global__ __launch_bounds__(256) void gather_kernel(const int* __restrict__ rowptr,
                                                     const int* __restrict__ csr_src,
                                                     const float* __restrict__ dinv,
                                                     const float* __restrict__ h,
                                                     const float* __restrict__ b,
                                                     float* __restrict__ out, int n) {
    const int wave = (blockIdx.x * blockDim.x + threadIdx.x) >> 6;
    const int lane = threadIdx.x & 63;
    if (wave >= n) return;
    const int c = wave;
    const float dc = dinv[c];

    float acc = 0.f;
    if (lane < F) acc = h[(size_t)c * F + lane] * dc * dc + b[lane];

    int e = rowptr[c];
    const int eEnd = rowptr[c + 1];
    for (; e + 1 < eEnd; e += 2) {
        int r0 = csr_src[e];
        int r1 = csr_src[e + 1];
        float n0 = dinv[r0] * dc;
        float n1 = dinv[r1] * dc;
        if (lane < F) {
            float v0 = h[(size_t)r0 * F + lane];
            float v1 = h[(size_t)r1 * F + lane];
            acc = fmaf(v0, n0, acc);
            acc = fmaf(v1, n1, acc);
        }
    }
    if (e < eEnd) {
        int r0 = csr_src[e];
        float n0 = dinv[r0] * dc;
        if (lane < F) acc = fmaf(h[(size_t)r0 * F + lane], n0, acc);
    }

    if (lane < F) out[(size_t)c * F + lane] = RELU ? fmaxf(acc, 0.f) : acc;
}

// ---------------- launch ----------------

extern "C" void kernel_launch(void* const* d_in, const int* in_sizes, int n_in,
                              void* d_out, int out_size, void* d_ws, size_t ws_size,
                              hipStream_t stream) {
    const float* x = (const float*)d_in[0];
    const int* row = (const int*)d_in[1];
    const int* col = row + N_EDGES;
    const float* W1 = (const float*)d_in[2];
    const float* b1 = (const float*)d_in[3];
    const float* W2 = (const float*)d_in[4];
    const float* b2 = (const float*)d_in[5];
    float* out = (float*)d_out;

    const int N = N_NODES, E = N_EDGES;
    const int NB = (N + 1023) / 1024;  // 98 scan blocks

    char* p = (char*)d_ws;
    auto alloc = [&](size_t bytes) {
        char* q = p;
        p += (bytes + 15) & ~(size_t)15;
        return q;
    };
    int* cnt = (int*)alloc((size_t)N * 4);
    int* rowptr = (int*)alloc((size_t)(N + 1) * 4);
    int* cursor = (int*)alloc((size_t)N * 4);
    int* csr_src = (int*)alloc((size_t)E * 4);
    int* blockSums = (int*)alloc((size_t)NB * 4);
    float* dinv = (float*)alloc((size_t)N * 4);
    float* h1 = (float*)alloc((size_t)N * HIDDEN * 4);
    float* agg1 = (float*)alloc((size_t)N * HIDDEN * 4);
    float* h2 = (float*)alloc((size_t)N * N_CLASSES * 4);

    // CSR build
    hipMemsetAsync(cnt, 0, (size_t)N * 4, stream);
    hist_kernel<<<(E + 255) / 256, 256, 0, stream>>>(col, cnt, E);
    dinv_kernel<<<(N + 255) / 256, 256, 0, stream>>>(cnt, dinv, N);
    block_sum_kernel<<<NB, 256, 0, stream>>>(cnt, blockSums, N);
    scan_sums_kernel<<<1, 256, 0, stream>>>(blockSums, NB);
    scan_write_kernel<<<NB, 256, 0, stream>>>(cnt, blockSums, rowptr, cursor, N);
    fill_kernel<<<(E + 255) / 256, 256, 0, stream>>>(row, col, cursor, csr_src, E);

    // layer 1
    gemm_kernel<N_FEAT, HIDDEN><<<(N + 63) / 64, 256, 0, stream>>>(x, W1, h1, N);
    gather_kernel<HIDDEN, true><<<(N + 3) / 4, 256, 0, stream>>>(rowptr, csr_src, dinv, h1,
                                                                 b1, agg1, N);

    // layer 2
    gemm_kernel<HIDDEN, N_CLASSES><<<(N + 63) / 64, 256, 0, stream>>>(agg1, W2, h2, N);
    gather_kernel<N_CLASSES, false><<<(N + 3) / 4, 256, 0, stream>>>(rowptr, csr_src, dinv, h2,
                                                                     b2, out, N);
}

// Round 4
// 404.909 us; speedup vs baseline: 4.8411x; 1.1441x over previous
//
#include <hip/hip_runtime.h>
#include <hip/hip_fp16.h>

#define N_NODES 100000
#define N_EDGES 1200000
#define N_FEAT 128
#define HIDDEN 64
#define N_CLASSES 40

// ---------------- CSR build ----------------

__global__ void hist_kernel(const int* __restrict__ col, int* __restrict__ cnt, int e) {
    int i = blockIdx.x * blockDim.x + threadIdx.x;
    if (i < e) atomicAdd(&cnt[col[i]], 1);
}

__global__ void dinv_kernel(const int* __restrict__ cnt, float* __restrict__ dinv, int n) {
    int i = blockIdx.x * blockDim.x + threadIdx.x;
    if (i < n) dinv[i] = rsqrtf((float)(cnt[i] + 1));  // +1 self loop
}

// ---- hierarchical exclusive scan ----
__global__ __launch_bounds__(256) void block_sum_kernel(const int* __restrict__ cnt,
                                                        int* __restrict__ blockSums, int n) {
    __shared__ int lds[256];
    const int b = blockIdx.x, t = threadIdx.x;
    const int base = b * 1024 + t * 4;
    int s = 0;
#pragma unroll
    for (int k = 0; k < 4; ++k) {
        int i = base + k;
        if (i < n) s += cnt[i];
    }
    lds[t] = s;
    __syncthreads();
    for (int d = 128; d > 0; d >>= 1) {
        if (t < d) lds[t] += lds[t + d];
        __syncthreads();
    }
    if (t == 0) blockSums[b] = lds[0];
}

__global__ __launch_bounds__(256) void scan_sums_kernel(int* __restrict__ blockSums, int nb) {
    __shared__ int lds[256];
    const int t = threadIdx.x;
    const int v = (t < nb) ? blockSums[t] : 0;
    lds[t] = v;
    __syncthreads();
    for (int d = 1; d < 256; d <<= 1) {
        int add = (t >= d) ? lds[t - d] : 0;
        __syncthreads();
        lds[t] += add;
        __syncthreads();
    }
    if (t < nb) blockSums[t] = lds[t] - v;  // exclusive
}

__global__ __launch_bounds__(256) void scan_write_kernel(const int* __restrict__ cnt,
                                                         const int* __restrict__ blockSums,
                                                         int* __restrict__ rowptr,
                                                         int* __restrict__ cursor, int n) {
    __shared__ int lds[256];
    const int b = blockIdx.x, t = threadIdx.x;
    const int base = b * 1024 + t * 4;
    int v[4];
    int s = 0;
#pragma unroll
    for (int k = 0; k < 4; ++k) {
        int i = base + k;
        v[k] = (i < n) ? cnt[i] : 0;
        s += v[k];
    }
    lds[t] = s;
    __syncthreads();
    for (int d = 1; d < 256; d <<= 1) {
        int add = (t >= d) ? lds[t - d] : 0;
        __syncthreads();
        lds[t] += add;
        __syncthreads();
    }
    int off = blockSums[b] + lds[t] - s;
#pragma unroll
    for (int k = 0; k < 4; ++k) {
        int i = base + k;
        if (i < n) {
            rowptr[i] = off;
            cursor[i] = off;
        }
        off += v[k];
    }
    if (b == 0 && t == 0) rowptr[n] = N_EDGES;
}

__global__ void fill_kernel(const int* __restrict__ row, const int* __restrict__ col,
                            int* __restrict__ cursor, int* __restrict__ csr_src, int e) {
    int i = blockIdx.x * blockDim.x + threadIdx.x;
    if (i < e) {
        int c = col[i];
        int pos = atomicAdd(&cursor[c], 1);
        csr_src[pos] = row[i];
    }
}

// ---------------- tiled GEMM with scaled-fp16 epilogue ----------------
// Hs[node,f] = (float16)( (X @ W)[node,f] * dinv[node] )

template <int K, int NOUT>
__global__ __launch_bounds__(256) void gemm_scaled_kernel(const float* __restrict__ X,
                                                          const float* __restrict__ W,
                                                          const float* __restrict__ dinv,
                                                          __half* __restrict__ Hs, int M) {
    constexpr int TI = 16;
    constexpr int TJ = NOUT / 4;
    constexpr int BN = 64;
    constexpr int XPITCH = BN + 4;

    __shared__ float ws[K * NOUT];
    __shared__ float xs[K * XPITCH];

    const int tid = threadIdx.x;
    const int node0 = blockIdx.x * BN;

    for (int i = tid; i < K * NOUT; i += 256) ws[i] = W[i];

    constexpr int NF4 = BN * (K / 4);
    for (int idx = tid; idx < NF4; idx += 256) {
        int node = idx / (K / 4);
        int k4 = idx % (K / 4);
        float4 v = make_float4(0.f, 0.f, 0.f, 0.f);
        if (node0 + node < M) v = *(const float4*)&X[(size_t)(node0 + node) * K + k4 * 4];
        xs[(k4 * 4 + 0) * XPITCH + node] = v.x;
        xs[(k4 * 4 + 1) * XPITCH + node] = v.y;
        xs[(k4 * 4 + 2) * XPITCH + node] = v.z;
        xs[(k4 * 4 + 3) * XPITCH + node] = v.w;
    }
    __syncthreads();

    if (tid < TI * TJ) {
        const int ti = tid % TI;
        const int tj = tid / TI;
        float acc[4][4];
#pragma unroll
        for (int a = 0; a < 4; ++a)
#pragma unroll
            for (int b = 0; b < 4; ++b) acc[a][b] = 0.f;

        for (int k = 0; k < K; ++k) {
            float4 xv = *(const float4*)&xs[k * XPITCH + ti * 4];
            float4 wv = *(const float4*)&ws[k * NOUT + tj * 4];
            const float xa[4] = {xv.x, xv.y, xv.z, xv.w};
            const float wb[4] = {wv.x, wv.y, wv.z, wv.w};
#pragma unroll
            for (int a = 0; a < 4; ++a)
#pragma unroll
                for (int b = 0; b < 4; ++b) acc[a][b] = fmaf(xa[a], wb[b], acc[a][b]);
        }

#pragma unroll
        for (int a = 0; a < 4; ++a) {
            int node = node0 + ti * 4 + a;
            if (node < M) {
                float s = dinv[node];
                __half2 p0 = __floats2half2_rn(acc[a][0] * s, acc[a][1] * s);
                __half2 p1 = __floats2half2_rn(acc[a][2] * s, acc[a][3] * s);
                uint2 packed;
                packed.x = *(unsigned int*)&p0;
                packed.y = *(unsigned int*)&p1;
                *(uint2*)&Hs[(size_t)node * NOUT + tj * 4] = packed;
            }
        }
    }
}

// ---------------- per-node wave gather (fp16 pre-scaled rows) ----------------
// out[c,f] = (relu?)( dinv[c] * ( hs[c,f] + sum_{r in in(c)} hs[r,f] ) + b[f] )

template <int F, bool RELU>
__global__ __launch_bounds__(256) void gather_kernel(const int* __restrict__ rowptr,
                                                     const int* __restrict__ csr_src,
                                                     const float* __restrict__ dinv,
                                                     const __half* __restrict__ hs,
                                                     const float* __restrict__ b,
                                                     float* __restrict__ out, int n) {
    const int wave = (blockIdx.x * blockDim.x + threadIdx.x) >> 6;
    const int lane = threadIdx.x & 63;
    if (wave >= n) return;
    const int c = wave;
    const float dc = dinv[c];

    float acc = 0.f;
    if (lane < F) acc = __half2float(hs[(size_t)c * F + lane]);  // self loop (pre-scaled)

    int e = rowptr[c];
    const int eEnd = rowptr[c + 1];
    for (; e + 3 < eEnd; e += 4) {
        int r0 = csr_src[e];
        int r1 = csr_src[e + 1];
        int r2 = csr_src[e + 2];
        int r3 = csr_src[e + 3];
        if (lane < F) {
            float v0 = __half2float(hs[(size_t)r0 * F + lane]);
            float v1 = __half2float(hs[(size_t)r1 * F + lane]);
            float v2 = __half2float(hs[(size_t)r2 * F + lane]);
            float v3 = __half2float(hs[(size_t)r3 * F + lane]);
            acc += v0 + v1 + v2 + v3;
        }
    }
    for (; e < eEnd; ++e) {
        int r0 = csr_src[e];
        if (lane < F) acc += __half2float(hs[(size_t)r0 * F + lane]);
    }

    if (lane < F) {
        float v = fmaf(acc, dc, b[lane]);
        out[(size_t)c * F + lane] = RELU ? fmaxf(v, 0.f) : v;
    }
}

// ---------------- launch ----------------

extern "C" void kernel_launch(void* const* d_in, const int* in_sizes, int n_in,
                              void* d_out, int out_size, void* d_ws, size_t ws_size,
                              hipStream_t stream) {
    const float* x = (const float*)d_in[0];
    const int* row = (const int*)d_in[1];
    const int* col = row + N_EDGES;
    const float* W1 = (const float*)d_in[2];
    const float* b1 = (const float*)d_in[3];
    const float* W2 = (const float*)d_in[4];
    const float* b2 = (const float*)d_in[5];
    float* out = (float*)d_out;

    const int N = N_NODES, E = N_EDGES;
    const int NB = (N + 1023) / 1024;

    char* p = (char*)d_ws;
    auto alloc = [&](size_t bytes) {
        char* q = p;
        p += (bytes + 15) & ~(size_t)15;
        return q;
    };
    int* cnt = (int*)alloc((size_t)N * 4);
    int* rowptr = (int*)alloc((size_t)(N + 1) * 4);
    int* cursor = (int*)alloc((size_t)N * 4);
    int* csr_src = (int*)alloc((size_t)E * 4);
    int* blockSums = (int*)alloc((size_t)NB * 4);
    float* dinv = (float*)alloc((size_t)N * 4);
    __half* h1s = (__half*)alloc((size_t)N * HIDDEN * 2);
    float* agg1 = (float*)alloc((size_t)N * HIDDEN * 4);
    __half* h2s = (__half*)alloc((size_t)N * N_CLASSES * 2);

    // CSR build
    hipMemsetAsync(cnt, 0, (size_t)N * 4, stream);
    hist_kernel<<<(E + 255) / 256, 256, 0, stream>>>(col, cnt, E);
    dinv_kernel<<<(N + 255) / 256, 256, 0, stream>>>(cnt, dinv, N);
    block_sum_kernel<<<NB, 256, 0, stream>>>(cnt, blockSums, N);
    scan_sums_kernel<<<1, 256, 0, stream>>>(blockSums, NB);
    scan_write_kernel<<<NB, 256, 0, stream>>>(cnt, blockSums, rowptr, cursor, N);
    fill_kernel<<<(E + 255) / 256, 256, 0, stream>>>(row, col, cursor, csr_src, E);

    // layer 1
    gemm_scaled_kernel<N_FEAT, HIDDEN><<<(N + 63) / 64, 256, 0, stream>>>(x, W1, dinv, h1s, N);
    gather_kernel<HIDDEN, true><<<(N + 3) / 4, 256, 0, stream>>>(rowptr, csr_src, dinv, h1s,
                                                                 b1, agg1, N);

    // layer 2
    gemm_scaled_kernel<HIDDEN, N_CLASSES><<<(N + 63) / 64, 256, 0, stream>>>(agg1, W2, dinv,
                                                                             h2s, N);
    gather_kernel<N_CLASSES, false><<<(N + 3) / 4, 256, 0, stream>>>(rowptr, csr_src, dinv,
                                                                     h2s, b2, out, N);
}

// Round 5
// 367.819 us; speedup vs baseline: 5.3293x; 1.1008x over previous
//
#include <hip/hip_runtime.h>
#include <hip/hip_fp16.h>

#define N_NODES 100000
#define N_EDGES 1200000
#define N_FEAT 128
#define HIDDEN 64
#define N_CLASSES 40

// bucket sort parameters
#define BSHIFT 9
#define BMASK 511
#define BUCKET_NODES 512
#define NBK ((N_NODES + BUCKET_NODES - 1) / BUCKET_NODES)  // 196
#define BCAP 8192                                          // >> expected 6122, 26 sigma
#define CHUNK 4096

// ---------------- CSR build ----------------

__global__ void hist_kernel(const int* __restrict__ col, int* __restrict__ cnt, int e) {
    int i = blockIdx.x * blockDim.x + threadIdx.x;
    if (i < e) atomicAdd(&cnt[col[i]], 1);
}

__global__ void dinv_kernel(const int* __restrict__ cnt, float* __restrict__ dinv, int n) {
    int i = blockIdx.x * blockDim.x + threadIdx.x;
    if (i < n) dinv[i] = rsqrtf((float)(cnt[i] + 1));  // +1 self loop
}

// ---- hierarchical exclusive scan: cnt -> rowptr ----
__global__ __launch_bounds__(256) void block_sum_kernel(const int* __restrict__ cnt,
                                                        int* __restrict__ blockSums, int n) {
    __shared__ int lds[256];
    const int b = blockIdx.x, t = threadIdx.x;
    const int base = b * 1024 + t * 4;
    int s = 0;
#pragma unroll
    for (int k = 0; k < 4; ++k) {
        int i = base + k;
        if (i < n) s += cnt[i];
    }
    lds[t] = s;
    __syncthreads();
    for (int d = 128; d > 0; d >>= 1) {
        if (t < d) lds[t] += lds[t + d];
        __syncthreads();
    }
    if (t == 0) blockSums[b] = lds[0];
}

__global__ __launch_bounds__(256) void scan_sums_kernel(int* __restrict__ blockSums, int nb) {
    __shared__ int lds[256];
    const int t = threadIdx.x;
    const int v = (t < nb) ? blockSums[t] : 0;
    lds[t] = v;
    __syncthreads();
    for (int d = 1; d < 256; d <<= 1) {
        int add = (t >= d) ? lds[t - d] : 0;
        __syncthreads();
        lds[t] += add;
        __syncthreads();
    }
    if (t < nb) blockSums[t] = lds[t] - v;  // exclusive
}

__global__ __launch_bounds__(256) void scan_write_kernel(const int* __restrict__ cnt,
                                                         const int* __restrict__ blockSums,
                                                         int* __restrict__ rowptr, int n) {
    __shared__ int lds[256];
    const int b = blockIdx.x, t = threadIdx.x;
    const int base = b * 1024 + t * 4;
    int v[4];
    int s = 0;
#pragma unroll
    for (int k = 0; k < 4; ++k) {
        int i = base + k;
        v[k] = (i < n) ? cnt[i] : 0;
        s += v[k];
    }
    lds[t] = s;
    __syncthreads();
    for (int d = 1; d < 256; d <<= 1) {
        int add = (t >= d) ? lds[t - d] : 0;
        __syncthreads();
        lds[t] += add;
        __syncthreads();
    }
    int off = blockSums[b] + lds[t] - s;
#pragma unroll
    for (int k = 0; k < 4; ++k) {
        int i = base + k;
        if (i < n) rowptr[i] = off;
        off += v[k];
    }
    if (b == 0 && t == 0) rowptr[n] = N_EDGES;
}

// ---- bucket pass: edges -> bucket-major packed array (block-aggregated writes) ----

__global__ void init_gcursor_kernel(int* __restrict__ gcursor) {
    int i = blockIdx.x * blockDim.x + threadIdx.x;
    if (i < NBK) gcursor[i] = i * BCAP;
}

__global__ __launch_bounds__(256) void bucket_kernel(const int* __restrict__ row,
                                                     const int* __restrict__ col,
                                                     int* __restrict__ gcursor,
                                                     unsigned* __restrict__ bke, int E) {
    __shared__ int hist[NBK];
    __shared__ int pfx[NBK];
    __shared__ int gbase[NBK];
    __shared__ int lcnt[NBK];
    __shared__ unsigned ord[CHUNK];
    __shared__ unsigned char obkt[CHUNK];

    const int t = threadIdx.x;
    const int e0 = blockIdx.x * CHUNK;
    const int nE = min(CHUNK, E - e0);

    for (int i = t; i < NBK; i += 256) {
        hist[i] = 0;
        lcnt[i] = 0;
    }
    __syncthreads();

    for (int i = t; i < nE; i += 256) atomicAdd(&hist[col[e0 + i] >> BSHIFT], 1);
    __syncthreads();

    // exclusive prefix over NBK (<=256) buckets
    int v = (t < NBK) ? hist[t] : 0;
    if (t < NBK) pfx[t] = v;
    __syncthreads();
    for (int d = 1; d < 256; d <<= 1) {
        int add = (t >= d && t < NBK) ? pfx[t - d] : 0;
        __syncthreads();
        if (t < NBK) pfx[t] += add;
        __syncthreads();
    }
    if (t < NBK) {
        pfx[t] -= v;  // exclusive
        gbase[t] = (v > 0) ? atomicAdd(&gcursor[t], v) : 0;
    }
    __syncthreads();

    // place into LDS, bucket-contiguous
    for (int i = t; i < nE; i += 256) {
        int r = row[e0 + i];
        int c = col[e0 + i];
        int b = c >> BSHIFT;
        int pos = pfx[b] + atomicAdd(&lcnt[b], 1);
        ord[pos] = ((unsigned)r << BSHIFT) | (unsigned)(c & BMASK);
        obkt[pos] = (unsigned char)b;
    }
    __syncthreads();

    // write runs per bucket (contiguous within this block's reservation)
    for (int i = t; i < nE; i += 256) {
        int b = obkt[i];
        bke[(size_t)gbase[b] + (i - pfx[b])] = ord[i];
    }
}

// ---- per-bucket counting placement -> final CSR (single-writer contiguous region) ----

__global__ __launch_bounds__(256) void csr_from_buckets_kernel(const int* __restrict__ gcursor,
                                                               const unsigned* __restrict__ bke,
                                                               const int* __restrict__ rowptr,
                                                               int* __restrict__ csr_src,
                                                               int n) {
    __shared__ int cur[BUCKET_NODES];
    const int b = blockIdx.x, t = threadIdx.x;
    const int node0 = b << BSHIFT;
    const int nNodes = min(BUCKET_NODES, n - node0);

    for (int i = t; i < nNodes; i += 256) cur[i] = rowptr[node0 + i];
    __syncthreads();

    const int nb = gcursor[b] - b * BCAP;
    const unsigned* src = bke + (size_t)b * BCAP;
    for (int i = t; i < nb; i += 256) {
        unsigned p = src[i];
        int pos = atomicAdd(&cur[p & BMASK], 1);
        csr_src[pos] = (int)(p >> BSHIFT);
    }
}

// ---------------- tiled GEMM with scaled-fp16 epilogue ----------------

template <int K, int NOUT>
__global__ __launch_bounds__(256) void gemm_scaled_kernel(const float* __restrict__ X,
                                                          const float* __restrict__ W,
                                                          const float* __restrict__ dinv,
                                                          __half* __restrict__ Hs, int M) {
    constexpr int TI = 16;
    constexpr int TJ = NOUT / 4;
    constexpr int BN = 64;
    constexpr int XPITCH = BN + 4;

    __shared__ float ws[K * NOUT];
    __shared__ float xs[K * XPITCH];

    const int tid = threadIdx.x;
    const int node0 = blockIdx.x * BN;

    for (int i = tid; i < K * NOUT; i += 256) ws[i] = W[i];

    constexpr int NF4 = BN * (K / 4);
    for (int idx = tid; idx < NF4; idx += 256) {
        int node = idx / (K / 4);
        int k4 = idx % (K / 4);
        float4 v = make_float4(0.f, 0.f, 0.f, 0.f);
        if (node0 + node < M) v = *(const float4*)&X[(size_t)(node0 + node) * K + k4 * 4];
        xs[(k4 * 4 + 0) * XPITCH + node] = v.x;
        xs[(k4 * 4 + 1) * XPITCH + node] = v.y;
        xs[(k4 * 4 + 2) * XPITCH + node] = v.z;
        xs[(k4 * 4 + 3) * XPITCH + node] = v.w;
    }
    __syncthreads();

    if (tid < TI * TJ) {
        const int ti = tid % TI;
        const int tj = tid / TI;
        float acc[4][4];
#pragma unroll
        for (int a = 0; a < 4; ++a)
#pragma unroll
            for (int b = 0; b < 4; ++b) acc[a][b] = 0.f;

        for (int k = 0; k < K; ++k) {
            float4 xv = *(const float4*)&xs[k * XPITCH + ti * 4];
            float4 wv = *(const float4*)&ws[k * NOUT + tj * 4];
            const float xa[4] = {xv.x, xv.y, xv.z, xv.w};
            const float wb[4] = {wv.x, wv.y, wv.z, wv.w};
#pragma unroll
            for (int a = 0; a < 4; ++a)
#pragma unroll
                for (int b = 0; b < 4; ++b) acc[a][b] = fmaf(xa[a], wb[b], acc[a][b]);
        }

#pragma unroll
        for (int a = 0; a < 4; ++a) {
            int node = node0 + ti * 4 + a;
            if (node < M) {
                float s = dinv[node];
                __half2 p0 = __floats2half2_rn(acc[a][0] * s, acc[a][1] * s);
                __half2 p1 = __floats2half2_rn(acc[a][2] * s, acc[a][3] * s);
                uint2 packed;
                packed.x = *(unsigned int*)&p0;
                packed.y = *(unsigned int*)&p1;
                *(uint2*)&Hs[(size_t)node * NOUT + tj * 4] = packed;
            }
        }
    }
}

// ---------------- per-node wave gather (fp16 pre-scaled rows) ----------------

template <int F, bool RELU>
__global__ __launch_bounds__(256) void gather_kernel(const int* __restrict__ rowptr,
                                                     const int* __restrict__ csr_src,
                                                     const float* __restrict__ dinv,
                                                     const __half* __restrict__ hs,
                                                     const float* __restrict__ b,
                                                     float* __restrict__ out, int n) {
    const int wave = (blockIdx.x * blockDim.x + threadIdx.x) >> 6;
    const int lane = threadIdx.x & 63;
    if (wave >= n) return;
    const int c = wave;
    const float dc = dinv[c];

    float acc = 0.f;
    if (lane < F) acc = __half2float(hs[(size_t)c * F + lane]);  // self loop (pre-scaled)

    int e = rowptr[c];
    const int eEnd = rowptr[c + 1];
    for (; e + 3 < eEnd; e += 4) {
        int r0 = csr_src[e];
        int r1 = csr_src[e + 1];
        int r2 = csr_src[e + 2];
        int r3 = csr_src[e + 3];
        if (lane < F) {
            float v0 = __half2float(hs[(size_t)r0 * F + lane]);
            float v1 = __half2float(hs[(size_t)r1 * F + lane]);
            float v2 = __half2float(hs[(size_t)r2 * F + lane]);
            float v3 = __half2float(hs[(size_t)r3 * F + lane]);
            acc += v0 + v1 + v2 + v3;
        }
    }
    for (; e < eEnd; ++e) {
        int r0 = csr_src[e];
        if (lane < F) acc += __half2float(hs[(size_t)r0 * F + lane]);
    }

    if (lane < F) {
        float v = fmaf(acc, dc, b[lane]);
        out[(size_t)c * F + lane] = RELU ? fmaxf(v, 0.f) : v;
    }
}

// ---------------- launch ----------------

extern "C" void kernel_launch(void* const* d_in, const int* in_sizes, int n_in,
                              void* d_out, int out_size, void* d_ws, size_t ws_size,
                              hipStream_t stream) {
    const float* x = (const float*)d_in[0];
    const int* row = (const int*)d_in[1];
    const int* col = row + N_EDGES;
    const float* W1 = (const float*)d_in[2];
    const float* b1 = (const float*)d_in[3];
    const float* W2 = (const float*)d_in[4];
    const float* b2 = (const float*)d_in[5];
    float* out = (float*)d_out;

    const int N = N_NODES, E = N_EDGES;
    const int NB = (N + 1023) / 1024;

    char* p = (char*)d_ws;
    auto alloc = [&](size_t bytes) {
        char* q = p;
        p += (bytes + 15) & ~(size_t)15;
        return q;
    };
    int* cnt = (int*)alloc((size_t)N * 4);
    int* rowptr = (int*)alloc((size_t)(N + 1) * 4);
    int* csr_src = (int*)alloc((size_t)E * 4);
    int* blockSums = (int*)alloc((size_t)NB * 4);
    int* gcursor = (int*)alloc((size_t)NBK * 4);
    unsigned* bke = (unsigned*)alloc((size_t)NBK * BCAP * 4);
    float* dinv = (float*)alloc((size_t)N * 4);
    __half* h1s = (__half*)alloc((size_t)N * HIDDEN * 2);
    float* agg1 = (float*)alloc((size_t)N * HIDDEN * 4);
    __half* h2s = (__half*)alloc((size_t)N * N_CLASSES * 2);

    // CSR build
    hipMemsetAsync(cnt, 0, (size_t)N * 4, stream);
    hist_kernel<<<(E + 255) / 256, 256, 0, stream>>>(col, cnt, E);
    dinv_kernel<<<(N + 255) / 256, 256, 0, stream>>>(cnt, dinv, N);
    block_sum_kernel<<<NB, 256, 0, stream>>>(cnt, blockSums, N);
    scan_sums_kernel<<<1, 256, 0, stream>>>(blockSums, NB);
    scan_write_kernel<<<NB, 256, 0, stream>>>(cnt, blockSums, rowptr, N);
    init_gcursor_kernel<<<(NBK + 255) / 256, 256, 0, stream>>>(gcursor);
    bucket_kernel<<<(E + CHUNK - 1) / CHUNK, 256, 0, stream>>>(row, col, gcursor, bke, E);
    csr_from_buckets_kernel<<<NBK, 256, 0, stream>>>(gcursor, bke, rowptr, csr_src, N);

    // layer 1
    gemm_scaled_kernel<N_FEAT, HIDDEN><<<(N + 63) / 64, 256, 0, stream>>>(x, W1, dinv, h1s, N);
    gather_kernel<HIDDEN, true><<<(N + 3) / 4, 256, 0, stream>>>(rowptr, csr_src, dinv, h1s,
                                                                 b1, agg1, N);

    // layer 2
    gemm_scaled_kernel<HIDDEN, N_CLASSES><<<(N + 63) / 64, 256, 0, stream>>>(agg1, W2, dinv,
                                                                             h2s, N);
    gather_kernel<N_CLASSES, false><<<(N + 3) / 4, 256, 0, stream>>>(rowptr, csr_src, dinv,
                                                                     h2s, b2, out, N);
}

// Round 6
// 330.817 us; speedup vs baseline: 5.9254x; 1.1119x over previous
//
#include <hip/hip_runtime.h>
#include <hip/hip_fp16.h>

#define N_NODES 100000
#define N_EDGES 1200000
#define N_FEAT 128
#define HIDDEN 64
#define N_CLASSES 40

// bucket sort parameters
#define BSHIFT 9
#define BMASK 511
#define BUCKET_NODES 512
#define NBK ((N_NODES + BUCKET_NODES - 1) / BUCKET_NODES)  // 196
#define BCAP 8192
#define CHUNK 4096

// ---------------- CSR build ----------------

__global__ void hist_kernel(const int* __restrict__ col, int* __restrict__ cnt, int e) {
    int i = blockIdx.x * blockDim.x + threadIdx.x;
    if (i < e) atomicAdd(&cnt[col[i]], 1);
}

__global__ void dinv_kernel(const int* __restrict__ cnt, float* __restrict__ dinv, int n) {
    int i = blockIdx.x * blockDim.x + threadIdx.x;
    if (i < n) dinv[i] = rsqrtf((float)(cnt[i] + 1));  // +1 self loop
}

// ---- hierarchical exclusive scan: cnt -> rowptr ----
__global__ __launch_bounds__(256) void block_sum_kernel(const int* __restrict__ cnt,
                                                        int* __restrict__ blockSums, int n) {
    __shared__ int lds[256];
    const int b = blockIdx.x, t = threadIdx.x;
    const int base = b * 1024 + t * 4;
    int s = 0;
#pragma unroll
    for (int k = 0; k < 4; ++k) {
        int i = base + k;
        if (i < n) s += cnt[i];
    }
    lds[t] = s;
    __syncthreads();
    for (int d = 128; d > 0; d >>= 1) {
        if (t < d) lds[t] += lds[t + d];
        __syncthreads();
    }
    if (t == 0) blockSums[b] = lds[0];
}

__global__ __launch_bounds__(256) void scan_sums_kernel(int* __restrict__ blockSums, int nb) {
    __shared__ int lds[256];
    const int t = threadIdx.x;
    const int v = (t < nb) ? blockSums[t] : 0;
    lds[t] = v;
    __syncthreads();
    for (int d = 1; d < 256; d <<= 1) {
        int add = (t >= d) ? lds[t - d] : 0;
        __syncthreads();
        lds[t] += add;
        __syncthreads();
    }
    if (t < nb) blockSums[t] = lds[t] - v;  // exclusive
}

__global__ __launch_bounds__(256) void scan_write_kernel(const int* __restrict__ cnt,
                                                         const int* __restrict__ blockSums,
                                                         int* __restrict__ rowptr, int n) {
    __shared__ int lds[256];
    const int b = blockIdx.x, t = threadIdx.x;
    const int base = b * 1024 + t * 4;
    int v[4];
    int s = 0;
#pragma unroll
    for (int k = 0; k < 4; ++k) {
        int i = base + k;
        v[k] = (i < n) ? cnt[i] : 0;
        s += v[k];
    }
    lds[t] = s;
    __syncthreads();
    for (int d = 1; d < 256; d <<= 1) {
        int add = (t >= d) ? lds[t - d] : 0;
        __syncthreads();
        lds[t] += add;
        __syncthreads();
    }
    int off = blockSums[b] + lds[t] - s;
#pragma unroll
    for (int k = 0; k < 4; ++k) {
        int i = base + k;
        if (i < n) rowptr[i] = off;
        off += v[k];
    }
    if (b == 0 && t == 0) rowptr[n] = N_EDGES;
}

// ---- bucket pass: edges -> bucket-major packed array (block-aggregated writes) ----

__global__ void init_gcursor_kernel(int* __restrict__ gcursor) {
    int i = blockIdx.x * blockDim.x + threadIdx.x;
    if (i < NBK) gcursor[i] = i * BCAP;
}

__global__ __launch_bounds__(256) void bucket_kernel(const int* __restrict__ row,
                                                     const int* __restrict__ col,
                                                     int* __restrict__ gcursor,
                                                     unsigned* __restrict__ bke, int E) {
    __shared__ int hist[NBK];
    __shared__ int pfx[NBK];
    __shared__ int gbase[NBK];
    __shared__ int lcnt[NBK];
    __shared__ unsigned ord[CHUNK];
    __shared__ unsigned char obkt[CHUNK];

    const int t = threadIdx.x;
    const int e0 = blockIdx.x * CHUNK;
    const int nE = min(CHUNK, E - e0);

    for (int i = t; i < NBK; i += 256) {
        hist[i] = 0;
        lcnt[i] = 0;
    }
    __syncthreads();

    for (int i = t; i < nE; i += 256) atomicAdd(&hist[col[e0 + i] >> BSHIFT], 1);
    __syncthreads();

    int v = (t < NBK) ? hist[t] : 0;
    if (t < NBK) pfx[t] = v;
    __syncthreads();
    for (int d = 1; d < 256; d <<= 1) {
        int add = (t >= d && t < NBK) ? pfx[t - d] : 0;
        __syncthreads();
        if (t < NBK) pfx[t] += add;
        __syncthreads();
    }
    if (t < NBK) {
        pfx[t] -= v;  // exclusive
        gbase[t] = (v > 0) ? atomicAdd(&gcursor[t], v) : 0;
    }
    __syncthreads();

    for (int i = t; i < nE; i += 256) {
        int r = row[e0 + i];
        int c = col[e0 + i];
        int b = c >> BSHIFT;
        int pos = pfx[b] + atomicAdd(&lcnt[b], 1);
        ord[pos] = ((unsigned)r << BSHIFT) | (unsigned)(c & BMASK);
        obkt[pos] = (unsigned char)b;
    }
    __syncthreads();

    for (int i = t; i < nE; i += 256) {
        int b = obkt[i];
        bke[(size_t)gbase[b] + (i - pfx[b])] = ord[i];
    }
}

__global__ __launch_bounds__(256) void csr_from_buckets_kernel(const int* __restrict__ gcursor,
                                                               const unsigned* __restrict__ bke,
                                                               const int* __restrict__ rowptr,
                                                               int* __restrict__ csr_src,
                                                               int n) {
    __shared__ int cur[BUCKET_NODES];
    const int b = blockIdx.x, t = threadIdx.x;
    const int node0 = b << BSHIFT;
    const int nNodes = min(BUCKET_NODES, n - node0);

    for (int i = t; i < nNodes; i += 256) cur[i] = rowptr[node0 + i];
    __syncthreads();

    const int nb = gcursor[b] - b * BCAP;
    const unsigned* src = bke + (size_t)b * BCAP;
    for (int i = t; i < nb; i += 256) {
        unsigned p = src[i];
        int pos = atomicAdd(&cur[p & BMASK], 1);
        csr_src[pos] = (int)(p >> BSHIFT);
    }
}

// ---------------- tiled GEMM with scaled-fp16 epilogue ----------------
// Hs[node, 0..NOUT) = fp16( (X @ W)[node,:] * dinv[node] ), row stride OSTRIDE halves.

template <int K, int NOUT, int OSTRIDE>
__global__ __launch_bounds__(256) void gemm_scaled_kernel(const float* __restrict__ X,
                                                          const float* __restrict__ W,
                                                          const float* __restrict__ dinv,
                                                          __half* __restrict__ Hs, int M) {
    constexpr int TI = 16;
    constexpr int TJ = NOUT / 4;
    constexpr int BN = 64;
    constexpr int XPITCH = BN + 4;

    __shared__ float ws[K * NOUT];
    __shared__ float xs[K * XPITCH];

    const int tid = threadIdx.x;
    const int node0 = blockIdx.x * BN;

    for (int i = tid; i < K * NOUT; i += 256) ws[i] = W[i];

    constexpr int NF4 = BN * (K / 4);
    for (int idx = tid; idx < NF4; idx += 256) {
        int node = idx / (K / 4);
        int k4 = idx % (K / 4);
        float4 v = make_float4(0.f, 0.f, 0.f, 0.f);
        if (node0 + node < M) v = *(const float4*)&X[(size_t)(node0 + node) * K + k4 * 4];
        xs[(k4 * 4 + 0) * XPITCH + node] = v.x;
        xs[(k4 * 4 + 1) * XPITCH + node] = v.y;
        xs[(k4 * 4 + 2) * XPITCH + node] = v.z;
        xs[(k4 * 4 + 3) * XPITCH + node] = v.w;
    }
    __syncthreads();

    if (tid < TI * TJ) {
        const int ti = tid % TI;
        const int tj = tid / TI;
        float acc[4][4];
#pragma unroll
        for (int a = 0; a < 4; ++a)
#pragma unroll
            for (int b = 0; b < 4; ++b) acc[a][b] = 0.f;

        for (int k = 0; k < K; ++k) {
            float4 xv = *(const float4*)&xs[k * XPITCH + ti * 4];
            float4 wv = *(const float4*)&ws[k * NOUT + tj * 4];
            const float xa[4] = {xv.x, xv.y, xv.z, xv.w};
            const float wb[4] = {wv.x, wv.y, wv.z, wv.w};
#pragma unroll
            for (int a = 0; a < 4; ++a)
#pragma unroll
                for (int b = 0; b < 4; ++b) acc[a][b] = fmaf(xa[a], wb[b], acc[a][b]);
        }

#pragma unroll
        for (int a = 0; a < 4; ++a) {
            int node = node0 + ti * 4 + a;
            if (node < M) {
                float s = dinv[node];
                __half2 p0 = __floats2half2_rn(acc[a][0] * s, acc[a][1] * s);
                __half2 p1 = __floats2half2_rn(acc[a][2] * s, acc[a][3] * s);
                uint2 packed;
                packed.x = *(unsigned int*)&p0;
                packed.y = *(unsigned int*)&p1;
                *(uint2*)&Hs[(size_t)node * OSTRIDE + tj * 4] = packed;
            }
        }
    }
}

// ---------------- per-node wave gather, 8 row-slots x 8 chunk-lanes ----------------
// hs rows have stride 64 halves. Lane = slot g (0..7) x chunk q (0..7); each lane
// loads uint4 = 8 fp16 feats of its slot's source row. Butterfly-combine across g.
// out[c, f] = (relu?)( dinv[c] * (hs[c,f] + sum_in hs[r,f]) + b[f] )

__device__ inline void acc_row8(float (&acc)[8], uint4 u) {
    const __half2* hp = (const __half2*)&u;
#pragma unroll
    for (int k = 0; k < 4; ++k) {
        float2 f = __half22float2(hp[k]);
        acc[2 * k] += f.x;
        acc[2 * k + 1] += f.y;
    }
}

template <int FCHUNKS, bool RELU>  // FCHUNKS = valid 8-feature chunks (8 for 64, 5 for 40)
__global__ __launch_bounds__(256) void gather8_kernel(const int* __restrict__ rowptr,
                                                      const int* __restrict__ csr_src,
                                                      const float* __restrict__ dinv,
                                                      const __half* __restrict__ hs,
                                                      const float* __restrict__ b,
                                                      float* __restrict__ out, int n,
                                                      int outStride) {
    const int wave = (blockIdx.x * blockDim.x + threadIdx.x) >> 6;
    const int lane = threadIdx.x & 63;
    if (wave >= n) return;
    const int c = wave;
    const int g = lane >> 3;  // row slot
    const int q = lane & 7;   // 16B chunk within row
    const bool qv = q < FCHUNKS;

    const float dc = dinv[c];
    const int eBeg = rowptr[c];
    const int eEnd = rowptr[c + 1];

    float acc[8];
#pragma unroll
    for (int j = 0; j < 8; ++j) acc[j] = 0.f;

    // self loop: slot 0 only
    if (g == 0 && qv) {
        uint4 u = *(const uint4*)&hs[(size_t)c * 64 + q * 8];
        acc_row8(acc, u);
    }

    for (int e = eBeg; e < eEnd; e += 16) {
        const int i0 = e + g;
        const int i1 = e + 8 + g;
        int r0 = (i0 < eEnd) ? csr_src[i0] : -1;
        int r1 = (i1 < eEnd) ? csr_src[i1] : -1;
        uint4 u0 = make_uint4(0, 0, 0, 0);
        uint4 u1 = make_uint4(0, 0, 0, 0);
        if (r0 >= 0 && qv) u0 = *(const uint4*)&hs[(size_t)r0 * 64 + q * 8];
        if (r1 >= 0 && qv) u1 = *(const uint4*)&hs[(size_t)r1 * 64 + q * 8];
        acc_row8(acc, u0);
        acc_row8(acc, u1);
    }

    // combine partial sums across the 8 row slots (same q)
#pragma unroll
    for (int m = 8; m <= 32; m <<= 1)
#pragma unroll
        for (int j = 0; j < 8; ++j) acc[j] += __shfl_xor(acc[j], m, 64);

    if (g == 0 && qv) {
        float o[8];
#pragma unroll
        for (int j = 0; j < 8; ++j) {
            float v = fmaf(acc[j], dc, b[q * 8 + j]);
            o[j] = RELU ? fmaxf(v, 0.f) : v;
        }
        float* dst = &out[(size_t)c * outStride + q * 8];
        *(float4*)dst = make_float4(o[0], o[1], o[2], o[3]);
        *(float4*)(dst + 4) = make_float4(o[4], o[5], o[6], o[7]);
    }
}

// ---------------- launch ----------------

extern "C" void kernel_launch(void* const* d_in, const int* in_sizes, int n_in,
                              void* d_out, int out_size, void* d_ws, size_t ws_size,
                              hipStream_t stream) {
    const float* x = (const float*)d_in[0];
    const int* row = (const int*)d_in[1];
    const int* col = row + N_EDGES;
    const float* W1 = (const float*)d_in[2];
    const float* b1 = (const float*)d_in[3];
    const float* W2 = (const float*)d_in[4];
    const float* b2 = (const float*)d_in[5];
    float* out = (float*)d_out;

    const int N = N_NODES, E = N_EDGES;
    const int NB = (N + 1023) / 1024;

    char* p = (char*)d_ws;
    auto alloc = [&](size_t bytes) {
        char* q = p;
        p += (bytes + 15) & ~(size_t)15;
        return q;
    };
    int* cnt = (int*)alloc((size_t)N * 4);
    int* rowptr = (int*)alloc((size_t)(N + 1) * 4);
    int* csr_src = (int*)alloc((size_t)E * 4);
    int* blockSums = (int*)alloc((size_t)NB * 4);
    int* gcursor = (int*)alloc((size_t)NBK * 4);
    unsigned* bke = (unsigned*)alloc((size_t)NBK * BCAP * 4);
    float* dinv = (float*)alloc((size_t)N * 4);
    __half* h1s = (__half*)alloc((size_t)N * HIDDEN * 2);       // stride 64
    float* agg1 = (float*)alloc((size_t)N * HIDDEN * 4);
    __half* h2s = (__half*)alloc((size_t)N * HIDDEN * 2);       // 40 valid, stride 64

    // CSR build
    hipMemsetAsync(cnt, 0, (size_t)N * 4, stream);
    hist_kernel<<<(E + 255) / 256, 256, 0, stream>>>(col, cnt, E);
    dinv_kernel<<<(N + 255) / 256, 256, 0, stream>>>(cnt, dinv, N);
    block_sum_kernel<<<NB, 256, 0, stream>>>(cnt, blockSums, N);
    scan_sums_kernel<<<1, 256, 0, stream>>>(blockSums, NB);
    scan_write_kernel<<<NB, 256, 0, stream>>>(cnt, blockSums, rowptr, N);
    init_gcursor_kernel<<<(NBK + 255) / 256, 256, 0, stream>>>(gcursor);
    bucket_kernel<<<(E + CHUNK - 1) / CHUNK, 256, 0, stream>>>(row, col, gcursor, bke, E);
    csr_from_buckets_kernel<<<NBK, 256, 0, stream>>>(gcursor, bke, rowptr, csr_src, N);

    // layer 1
    gemm_scaled_kernel<N_FEAT, HIDDEN, HIDDEN>
        <<<(N + 63) / 64, 256, 0, stream>>>(x, W1, dinv, h1s, N);
    gather8_kernel<8, true><<<(N + 3) / 4, 256, 0, stream>>>(rowptr, csr_src, dinv, h1s, b1,
                                                             agg1, N, HIDDEN);

    // layer 2 (h2s rows padded to stride 64; pad never read)
    gemm_scaled_kernel<HIDDEN, N_CLASSES, HIDDEN>
        <<<(N + 63) / 64, 256, 0, stream>>>(agg1, W2, dinv, h2s, N);
    gather8_kernel<5, false><<<(N + 3) / 4, 256, 0, stream>>>(rowptr, csr_src, dinv, h2s, b2,
                                                              out, N, N_CLASSES);
}

// Round 7
// 299.440 us; speedup vs baseline: 6.5463x; 1.1048x over previous
//
#include <hip/hip_runtime.h>
#include <hip/hip_fp16.h>

#define N_NODES 100000
#define N_EDGES 1200000
#define N_FEAT 128
#define HIDDEN 64
#define N_CLASSES 40

// bucket sort parameters
#define BSHIFT 9
#define BMASK 511
#define BUCKET_NODES 512
#define NBK ((N_NODES + BUCKET_NODES - 1) / BUCKET_NODES)  // 196
#define BCAP 8192
#define CHUNK 4096

typedef _Float16 f16x8 __attribute__((ext_vector_type(8)));
typedef float f32x4 __attribute__((ext_vector_type(4)));

// ---------------- CSR build ----------------

__global__ void hist_kernel(const int* __restrict__ col, int* __restrict__ cnt, int e) {
    int i = blockIdx.x * blockDim.x + threadIdx.x;
    if (i < e) atomicAdd(&cnt[col[i]], 1);
}

__global__ void dinv_kernel(const int* __restrict__ cnt, float* __restrict__ dinv, int n) {
    int i = blockIdx.x * blockDim.x + threadIdx.x;
    if (i < n) dinv[i] = rsqrtf((float)(cnt[i] + 1));  // +1 self loop
}

// ---- hierarchical exclusive scan: cnt -> rowptr ----
__global__ __launch_bounds__(256) void block_sum_kernel(const int* __restrict__ cnt,
                                                        int* __restrict__ blockSums, int n) {
    __shared__ int lds[256];
    const int b = blockIdx.x, t = threadIdx.x;
    const int base = b * 1024 + t * 4;
    int s = 0;
#pragma unroll
    for (int k = 0; k < 4; ++k) {
        int i = base + k;
        if (i < n) s += cnt[i];
    }
    lds[t] = s;
    __syncthreads();
    for (int d = 128; d > 0; d >>= 1) {
        if (t < d) lds[t] += lds[t + d];
        __syncthreads();
    }
    if (t == 0) blockSums[b] = lds[0];
}

__global__ __launch_bounds__(256) void scan_sums_kernel(int* __restrict__ blockSums, int nb) {
    __shared__ int lds[256];
    const int t = threadIdx.x;
    const int v = (t < nb) ? blockSums[t] : 0;
    lds[t] = v;
    __syncthreads();
    for (int d = 1; d < 256; d <<= 1) {
        int add = (t >= d) ? lds[t - d] : 0;
        __syncthreads();
        lds[t] += add;
        __syncthreads();
    }
    if (t < nb) blockSums[t] = lds[t] - v;  // exclusive
}

__global__ __launch_bounds__(256) void scan_write_kernel(const int* __restrict__ cnt,
                                                         const int* __restrict__ blockSums,
                                                         int* __restrict__ rowptr, int n) {
    __shared__ int lds[256];
    const int b = blockIdx.x, t = threadIdx.x;
    const int base = b * 1024 + t * 4;
    int v[4];
    int s = 0;
#pragma unroll
    for (int k = 0; k < 4; ++k) {
        int i = base + k;
        v[k] = (i < n) ? cnt[i] : 0;
        s += v[k];
    }
    lds[t] = s;
    __syncthreads();
    for (int d = 1; d < 256; d <<= 1) {
        int add = (t >= d) ? lds[t - d] : 0;
        __syncthreads();
        lds[t] += add;
        __syncthreads();
    }
    int off = blockSums[b] + lds[t] - s;
#pragma unroll
    for (int k = 0; k < 4; ++k) {
        int i = base + k;
        if (i < n) rowptr[i] = off;
        off += v[k];
    }
    if (b == 0 && t == 0) rowptr[n] = N_EDGES;
}

// ---- bucket pass: edges -> bucket-major packed array (block-aggregated writes) ----

__global__ void init_gcursor_kernel(int* __restrict__ gcursor) {
    int i = blockIdx.x * blockDim.x + threadIdx.x;
    if (i < NBK) gcursor[i] = i * BCAP;
}

__global__ __launch_bounds__(256) void bucket_kernel(const int* __restrict__ row,
                                                     const int* __restrict__ col,
                                                     int* __restrict__ gcursor,
                                                     unsigned* __restrict__ bke, int E) {
    __shared__ int hist[NBK];
    __shared__ int pfx[NBK];
    __shared__ int gbase[NBK];
    __shared__ int lcnt[NBK];
    __shared__ unsigned ord[CHUNK];
    __shared__ unsigned char obkt[CHUNK];

    const int t = threadIdx.x;
    const int e0 = blockIdx.x * CHUNK;
    const int nE = min(CHUNK, E - e0);

    for (int i = t; i < NBK; i += 256) {
        hist[i] = 0;
        lcnt[i] = 0;
    }
    __syncthreads();

    for (int i = t; i < nE; i += 256) atomicAdd(&hist[col[e0 + i] >> BSHIFT], 1);
    __syncthreads();

    int v = (t < NBK) ? hist[t] : 0;
    if (t < NBK) pfx[t] = v;
    __syncthreads();
    for (int d = 1; d < 256; d <<= 1) {
        int add = (t >= d && t < NBK) ? pfx[t - d] : 0;
        __syncthreads();
        if (t < NBK) pfx[t] += add;
        __syncthreads();
    }
    if (t < NBK) {
        pfx[t] -= v;  // exclusive
        gbase[t] = (v > 0) ? atomicAdd(&gcursor[t], v) : 0;
    }
    __syncthreads();

    for (int i = t; i < nE; i += 256) {
        int r = row[e0 + i];
        int c = col[e0 + i];
        int b = c >> BSHIFT;
        int pos = pfx[b] + atomicAdd(&lcnt[b], 1);
        ord[pos] = ((unsigned)r << BSHIFT) | (unsigned)(c & BMASK);
        obkt[pos] = (unsigned char)b;
    }
    __syncthreads();

    for (int i = t; i < nE; i += 256) {
        int b = obkt[i];
        bke[(size_t)gbase[b] + (i - pfx[b])] = ord[i];
    }
}

__global__ __launch_bounds__(256) void csr_from_buckets_kernel(const int* __restrict__ gcursor,
                                                               const unsigned* __restrict__ bke,
                                                               const int* __restrict__ rowptr,
                                                               int* __restrict__ csr_src,
                                                               int n) {
    __shared__ int cur[BUCKET_NODES];
    const int b = blockIdx.x, t = threadIdx.x;
    const int node0 = b << BSHIFT;
    const int nNodes = min(BUCKET_NODES, n - node0);

    for (int i = t; i < nNodes; i += 256) cur[i] = rowptr[node0 + i];
    __syncthreads();

    const int nb = gcursor[b] - b * BCAP;
    const unsigned* src = bke + (size_t)b * BCAP;
    for (int i = t; i < nb; i += 256) {
        unsigned p = src[i];
        int pos = atomicAdd(&cur[p & BMASK], 1);
        csr_src[pos] = (int)(p >> BSHIFT);
    }
}

// ---------------- MFMA GEMM with scaled-fp16 epilogue ----------------
// Hs[node, f<NOUT] = fp16( (X @ W)[node,f] * dinv[node] ), row stride OSTRIDE halves.
// Block = 4 waves, 256 nodes. W (fp32 global) converted to fp16 in LDS; B-frags in
// registers (reused across 4 node-tiles/wave); A-frags loaded from global fp32 and
// converted in-flight. v_mfma_f32_16x16x32_f16 layouts (m89/m120 verified):
//   A[m=lane&15][k=quad*8+j], B[k=quad*8+j][n=lane&15], C: col=lane&15,row=quad*4+reg.

template <int K, int NOUT, int NOUT_PAD, int OSTRIDE>
__global__ __launch_bounds__(256) void gemm_mfma_kernel(const float* __restrict__ X,
                                                        const float* __restrict__ W,
                                                        const float* __restrict__ dinv,
                                                        __half* __restrict__ Hs, int M) {
    constexpr int KCH = K / 32;
    constexpr int NT = NOUT_PAD / 16;
    constexpr int WPITCH = NOUT_PAD + 2;  // spread banks for strided B-frag reads

    __shared__ _Float16 wh[K * WPITCH];
    __shared__ float sdinv[256];

    const int tid = threadIdx.x;
    const int bnode0 = blockIdx.x * 256;

    // stage W as fp16 (pad cols with 0)
    for (int i = tid; i < K * NOUT_PAD; i += 256) {
        int k = i / NOUT_PAD, n = i % NOUT_PAD;
        wh[k * WPITCH + n] = (n < NOUT) ? (_Float16)W[k * NOUT + n] : (_Float16)0.0f;
    }
    // stage dinv for the block's 256 nodes
    {
        int node = bnode0 + tid;
        sdinv[tid] = (node < M) ? dinv[node] : 0.f;
    }
    __syncthreads();

    const int wid = tid >> 6;
    const int lane = tid & 63;
    const int m = lane & 15;
    const int quad = lane >> 4;

    // B fragments
    f16x8 bf[KCH][NT];
#pragma unroll
    for (int kc = 0; kc < KCH; ++kc)
#pragma unroll
        for (int nt = 0; nt < NT; ++nt)
#pragma unroll
            for (int j = 0; j < 8; ++j)
                bf[kc][nt][j] = wh[(kc * 32 + quad * 8 + j) * WPITCH + nt * 16 + m];

    for (int nt4 = 0; nt4 < 4; ++nt4) {
        const int nb = bnode0 + wid * 64 + nt4 * 16;
        if (nb >= M) break;
        const int rowi = min(nb + m, M - 1);
        const float* xr = X + (size_t)rowi * K;

        f32x4 acc[NT];
#pragma unroll
        for (int nt = 0; nt < NT; ++nt) acc[nt] = (f32x4){0.f, 0.f, 0.f, 0.f};

#pragma unroll
        for (int kc = 0; kc < KCH; ++kc) {
            float4 u0 = *(const float4*)&xr[kc * 32 + quad * 8];
            float4 u1 = *(const float4*)&xr[kc * 32 + quad * 8 + 4];
            f16x8 af;
            af[0] = (_Float16)u0.x;
            af[1] = (_Float16)u0.y;
            af[2] = (_Float16)u0.z;
            af[3] = (_Float16)u0.w;
            af[4] = (_Float16)u1.x;
            af[5] = (_Float16)u1.y;
            af[6] = (_Float16)u1.z;
            af[7] = (_Float16)u1.w;
#pragma unroll
            for (int nt = 0; nt < NT; ++nt)
                acc[nt] = __builtin_amdgcn_mfma_f32_16x16x32_f16(af, bf[kc][nt], acc[nt], 0, 0, 0);
        }

        // epilogue: scale by dinv, store fp16
#pragma unroll
        for (int reg = 0; reg < 4; ++reg) {
            const int node = nb + quad * 4 + reg;
            if (node < M) {
                const float s = sdinv[node - bnode0];
#pragma unroll
                for (int nt = 0; nt < NT; ++nt) {
                    const int f = nt * 16 + m;
                    if (NOUT == NOUT_PAD || f < NOUT)
                        Hs[(size_t)node * OSTRIDE + f] = __float2half(acc[nt][reg] * s);
                }
            }
        }
    }
}

// ---------------- per-node wave gather, 8 row-slots x 8 chunk-lanes ----------------

__device__ inline void acc_row8(float (&acc)[8], uint4 u) {
    const __half2* hp = (const __half2*)&u;
#pragma unroll
    for (int k = 0; k < 4; ++k) {
        float2 f = __half22float2(hp[k]);
        acc[2 * k] += f.x;
        acc[2 * k + 1] += f.y;
    }
}

template <int FCHUNKS, bool RELU>  // FCHUNKS = valid 8-feature chunks (8 for 64, 5 for 40)
__global__ __launch_bounds__(256) void gather8_kernel(const int* __restrict__ rowptr,
                                                      const int* __restrict__ csr_src,
                                                      const float* __restrict__ dinv,
                                                      const __half* __restrict__ hs,
                                                      const float* __restrict__ b,
                                                      float* __restrict__ out, int n,
                                                      int outStride) {
    const int wave = (blockIdx.x * blockDim.x + threadIdx.x) >> 6;
    const int lane = threadIdx.x & 63;
    if (wave >= n) return;
    const int c = wave;
    const int g = lane >> 3;  // row slot
    const int q = lane & 7;   // 16B chunk within row
    const bool qv = q < FCHUNKS;

    const float dc = dinv[c];
    const int eBeg = rowptr[c];
    const int eEnd = rowptr[c + 1];

    float acc[8];
#pragma unroll
    for (int j = 0; j < 8; ++j) acc[j] = 0.f;

    // self loop: slot 0 only
    if (g == 0 && qv) {
        uint4 u = *(const uint4*)&hs[(size_t)c * 64 + q * 8];
        acc_row8(acc, u);
    }

    for (int e = eBeg; e < eEnd; e += 16) {
        const int i0 = e + g;
        const int i1 = e + 8 + g;
        int r0 = (i0 < eEnd) ? csr_src[i0] : -1;
        int r1 = (i1 < eEnd) ? csr_src[i1] : -1;
        uint4 u0 = make_uint4(0, 0, 0, 0);
        uint4 u1 = make_uint4(0, 0, 0, 0);
        if (r0 >= 0 && qv) u0 = *(const uint4*)&hs[(size_t)r0 * 64 + q * 8];
        if (r1 >= 0 && qv) u1 = *(const uint4*)&hs[(size_t)r1 * 64 + q * 8];
        acc_row8(acc, u0);
        acc_row8(acc, u1);
    }

    // combine partial sums across the 8 row slots (same q)
#pragma unroll
    for (int m = 8; m <= 32; m <<= 1)
#pragma unroll
        for (int j = 0; j < 8; ++j) acc[j] += __shfl_xor(acc[j], m, 64);

    if (g == 0 && qv) {
        float o[8];
#pragma unroll
        for (int j = 0; j < 8; ++j) {
            float v = fmaf(acc[j], dc, b[q * 8 + j]);
            o[j] = RELU ? fmaxf(v, 0.f) : v;
        }
        float* dst = &out[(size_t)c * outStride + q * 8];
        *(float4*)dst = make_float4(o[0], o[1], o[2], o[3]);
        *(float4*)(dst + 4) = make_float4(o[4], o[5], o[6], o[7]);
    }
}

// ---------------- launch ----------------

extern "C" void kernel_launch(void* const* d_in, const int* in_sizes, int n_in,
                              void* d_out, int out_size, void* d_ws, size_t ws_size,
                              hipStream_t stream) {
    const float* x = (const float*)d_in[0];
    const int* row = (const int*)d_in[1];
    const int* col = row + N_EDGES;
    const float* W1 = (const float*)d_in[2];
    const float* b1 = (const float*)d_in[3];
    const float* W2 = (const float*)d_in[4];
    const float* b2 = (const float*)d_in[5];
    float* out = (float*)d_out;

    const int N = N_NODES, E = N_EDGES;
    const int NB = (N + 1023) / 1024;

    char* p = (char*)d_ws;
    auto alloc = [&](size_t bytes) {
        char* q = p;
        p += (bytes + 15) & ~(size_t)15;
        return q;
    };
    int* cnt = (int*)alloc((size_t)N * 4);
    int* rowptr = (int*)alloc((size_t)(N + 1) * 4);
    int* csr_src = (int*)alloc((size_t)E * 4);
    int* blockSums = (int*)alloc((size_t)NB * 4);
    int* gcursor = (int*)alloc((size_t)NBK * 4);
    unsigned* bke = (unsigned*)alloc((size_t)NBK * BCAP * 4);
    float* dinv = (float*)alloc((size_t)N * 4);
    __half* h1s = (__half*)alloc((size_t)N * HIDDEN * 2);  // stride 64
    float* agg1 = (float*)alloc((size_t)N * HIDDEN * 4);
    __half* h2s = (__half*)alloc((size_t)N * HIDDEN * 2);  // 40 valid, stride 64

    // CSR build
    hipMemsetAsync(cnt, 0, (size_t)N * 4, stream);
    hist_kernel<<<(E + 255) / 256, 256, 0, stream>>>(col, cnt, E);
    dinv_kernel<<<(N + 255) / 256, 256, 0, stream>>>(cnt, dinv, N);
    block_sum_kernel<<<NB, 256, 0, stream>>>(cnt, blockSums, N);
    scan_sums_kernel<<<1, 256, 0, stream>>>(blockSums, NB);
    scan_write_kernel<<<NB, 256, 0, stream>>>(cnt, blockSums, rowptr, N);
    init_gcursor_kernel<<<(NBK + 255) / 256, 256, 0, stream>>>(gcursor);
    bucket_kernel<<<(E + CHUNK - 1) / CHUNK, 256, 0, stream>>>(row, col, gcursor, bke, E);
    csr_from_buckets_kernel<<<NBK, 256, 0, stream>>>(gcursor, bke, rowptr, csr_src, N);

    // layer 1
    gemm_mfma_kernel<N_FEAT, HIDDEN, HIDDEN, HIDDEN>
        <<<(N + 255) / 256, 256, 0, stream>>>(x, W1, dinv, h1s, N);
    gather8_kernel<8, true><<<(N + 3) / 4, 256, 0, stream>>>(rowptr, csr_src, dinv, h1s, b1,
                                                             agg1, N, HIDDEN);

    // layer 2 (NOUT 40 padded to 48 in-kernel; h2s rows stride 64, pad never read)
    gemm_mfma_kernel<HIDDEN, N_CLASSES, 48, HIDDEN>
        <<<(N + 255) / 256, 256, 0, stream>>>(agg1, W2, dinv, h2s, N);
    gather8_kernel<5, false><<<(N + 3) / 4, 256, 0, stream>>>(rowptr, csr_src, dinv, h2s, b2,
                                                              out, N, N_CLASSES);
}

// Round 8
// 254.754 us; speedup vs baseline: 7.6945x; 1.1754x over previous
//
#include <hip/hip_runtime.h>
#include <hip/hip_fp16.h>

#define N_NODES 100000
#define N_EDGES 1200000
#define N_FEAT 128
#define HIDDEN 64
#define N_CLASSES 40

// bucket sort parameters
#define BSHIFT 9
#define BMASK 511
#define BUCKET_NODES 512
#define NBK ((N_NODES + BUCKET_NODES - 1) / BUCKET_NODES)  // 196
#define BCAP 8192
#define CHUNK 4096

typedef _Float16 f16x8 __attribute__((ext_vector_type(8)));
typedef float f32x4 __attribute__((ext_vector_type(4)));

// ---- bucket pass: edges -> bucket-major packed array (block-aggregated writes) ----

__global__ void init_gcursor_kernel(int* __restrict__ gcursor) {
    int i = blockIdx.x * blockDim.x + threadIdx.x;
    if (i < NBK) gcursor[i] = i * BCAP;
}

__global__ __launch_bounds__(256) void bucket_kernel(const int* __restrict__ row,
                                                     const int* __restrict__ col,
                                                     int* __restrict__ gcursor,
                                                     unsigned* __restrict__ bke, int E) {
    __shared__ int hist[NBK];
    __shared__ int pfx[NBK];
    __shared__ int gbase[NBK];
    __shared__ int lcnt[NBK];
    __shared__ unsigned ord[CHUNK];
    __shared__ unsigned char obkt[CHUNK];

    const int t = threadIdx.x;
    const int e0 = blockIdx.x * CHUNK;
    const int nE = min(CHUNK, E - e0);

    for (int i = t; i < NBK; i += 256) {
        hist[i] = 0;
        lcnt[i] = 0;
    }
    __syncthreads();

    for (int i = t; i < nE; i += 256) atomicAdd(&hist[col[e0 + i] >> BSHIFT], 1);
    __syncthreads();

    int v = (t < NBK) ? hist[t] : 0;
    if (t < NBK) pfx[t] = v;
    __syncthreads();
    for (int d = 1; d < 256; d <<= 1) {
        int add = (t >= d && t < NBK) ? pfx[t - d] : 0;
        __syncthreads();
        if (t < NBK) pfx[t] += add;
        __syncthreads();
    }
    if (t < NBK) {
        pfx[t] -= v;  // exclusive
        gbase[t] = (v > 0) ? atomicAdd(&gcursor[t], v) : 0;
    }
    __syncthreads();

    for (int i = t; i < nE; i += 256) {
        int r = row[e0 + i];
        int c = col[e0 + i];
        int b = c >> BSHIFT;
        int pos = pfx[b] + atomicAdd(&lcnt[b], 1);
        ord[pos] = ((unsigned)r << BSHIFT) | (unsigned)(c & BMASK);
        obkt[pos] = (unsigned char)b;
    }
    __syncthreads();

    for (int i = t; i < nE; i += 256) {
        int b = obkt[i];
        bke[(size_t)gbase[b] + (i - pfx[b])] = ord[i];
    }
}

// ---- per-bucket degree count (LDS atomics, coalesced writes) + fused dinv ----

__global__ __launch_bounds__(256) void count_from_buckets_kernel(const int* __restrict__ gcursor,
                                                                 const unsigned* __restrict__ bke,
                                                                 int* __restrict__ cnt,
                                                                 float* __restrict__ dinv,
                                                                 int n) {
    __shared__ int lcnt[BUCKET_NODES];
    const int b = blockIdx.x, t = threadIdx.x;
    const int node0 = b << BSHIFT;
    const int nNodes = min(BUCKET_NODES, n - node0);

    for (int i = t; i < BUCKET_NODES; i += 256) lcnt[i] = 0;
    __syncthreads();

    const int nb = gcursor[b] - b * BCAP;
    const unsigned* src = bke + (size_t)b * BCAP;
    for (int i = t; i < nb; i += 256) atomicAdd(&lcnt[src[i] & BMASK], 1);
    __syncthreads();

    for (int i = t; i < nNodes; i += 256) {
        int c = lcnt[i];
        cnt[node0 + i] = c;
        dinv[node0 + i] = rsqrtf((float)(c + 1));  // +1 self loop
    }
}

// ---- hierarchical exclusive scan: cnt -> rowptr ----
__global__ __launch_bounds__(256) void block_sum_kernel(const int* __restrict__ cnt,
                                                        int* __restrict__ blockSums, int n) {
    __shared__ int lds[256];
    const int b = blockIdx.x, t = threadIdx.x;
    const int base = b * 1024 + t * 4;
    int s = 0;
#pragma unroll
    for (int k = 0; k < 4; ++k) {
        int i = base + k;
        if (i < n) s += cnt[i];
    }
    lds[t] = s;
    __syncthreads();
    for (int d = 128; d > 0; d >>= 1) {
        if (t < d) lds[t] += lds[t + d];
        __syncthreads();
    }
    if (t == 0) blockSums[b] = lds[0];
}

__global__ __launch_bounds__(256) void scan_sums_kernel(int* __restrict__ blockSums, int nb) {
    __shared__ int lds[256];
    const int t = threadIdx.x;
    const int v = (t < nb) ? blockSums[t] : 0;
    lds[t] = v;
    __syncthreads();
    for (int d = 1; d < 256; d <<= 1) {
        int add = (t >= d) ? lds[t - d] : 0;
        __syncthreads();
        lds[t] += add;
        __syncthreads();
    }
    if (t < nb) blockSums[t] = lds[t] - v;  // exclusive
}

__global__ __launch_bounds__(256) void scan_write_kernel(const int* __restrict__ cnt,
                                                         const int* __restrict__ blockSums,
                                                         int* __restrict__ rowptr, int n) {
    __shared__ int lds[256];
    const int b = blockIdx.x, t = threadIdx.x;
    const int base = b * 1024 + t * 4;
    int v[4];
    int s = 0;
#pragma unroll
    for (int k = 0; k < 4; ++k) {
        int i = base + k;
        v[k] = (i < n) ? cnt[i] : 0;
        s += v[k];
    }
    lds[t] = s;
    __syncthreads();
    for (int d = 1; d < 256; d <<= 1) {
        int add = (t >= d) ? lds[t - d] : 0;
        __syncthreads();
        lds[t] += add;
        __syncthreads();
    }
    int off = blockSums[b] + lds[t] - s;
#pragma unroll
    for (int k = 0; k < 4; ++k) {
        int i = base + k;
        if (i < n) rowptr[i] = off;
        off += v[k];
    }
    if (b == 0 && t == 0) rowptr[n] = N_EDGES;
}

__global__ __launch_bounds__(256) void csr_from_buckets_kernel(const int* __restrict__ gcursor,
                                                               const unsigned* __restrict__ bke,
                                                               const int* __restrict__ rowptr,
                                                               int* __restrict__ csr_src,
                                                               int n) {
    __shared__ int cur[BUCKET_NODES];
    const int b = blockIdx.x, t = threadIdx.x;
    const int node0 = b << BSHIFT;
    const int nNodes = min(BUCKET_NODES, n - node0);

    for (int i = t; i < nNodes; i += 256) cur[i] = rowptr[node0 + i];
    __syncthreads();

    const int nb = gcursor[b] - b * BCAP;
    const unsigned* src = bke + (size_t)b * BCAP;
    for (int i = t; i < nb; i += 256) {
        unsigned p = src[i];
        int pos = atomicAdd(&cur[p & BMASK], 1);
        csr_src[pos] = (int)(p >> BSHIFT);
    }
}

// ---------------- MFMA GEMM with scaled-fp16 epilogue ----------------
// Hs[node, f<NOUT] = fp16( (X @ W)[node,f] * dinv[node] ), row stride OSTRIDE halves.
// v_mfma_f32_16x16x32_f16 layouts (m89/m120 verified):
//   A[m=lane&15][k=quad*8+j], B[k=quad*8+j][n=lane&15], C: col=lane&15,row=quad*4+reg.

template <int K, int NOUT, int NOUT_PAD, int OSTRIDE>
__global__ __launch_bounds__(256) void gemm_mfma_kernel(const float* __restrict__ X,
                                                        const float* __restrict__ W,
                                                        const float* __restrict__ dinv,
                                                        __half* __restrict__ Hs, int M) {
    constexpr int KCH = K / 32;
    constexpr int NT = NOUT_PAD / 16;
    constexpr int WPITCH = NOUT_PAD + 2;

    __shared__ _Float16 wh[K * WPITCH];
    __shared__ float sdinv[256];

    const int tid = threadIdx.x;
    const int bnode0 = blockIdx.x * 256;

    for (int i = tid; i < K * NOUT_PAD; i += 256) {
        int k = i / NOUT_PAD, n = i % NOUT_PAD;
        wh[k * WPITCH + n] = (n < NOUT) ? (_Float16)W[k * NOUT + n] : (_Float16)0.0f;
    }
    {
        int node = bnode0 + tid;
        sdinv[tid] = (node < M) ? dinv[node] : 0.f;
    }
    __syncthreads();

    const int wid = tid >> 6;
    const int lane = tid & 63;
    const int m = lane & 15;
    const int quad = lane >> 4;

    f16x8 bf[KCH][NT];
#pragma unroll
    for (int kc = 0; kc < KCH; ++kc)
#pragma unroll
        for (int nt = 0; nt < NT; ++nt)
#pragma unroll
            for (int j = 0; j < 8; ++j)
                bf[kc][nt][j] = wh[(kc * 32 + quad * 8 + j) * WPITCH + nt * 16 + m];

    for (int nt4 = 0; nt4 < 4; ++nt4) {
        const int nb = bnode0 + wid * 64 + nt4 * 16;
        if (nb >= M) break;
        const int rowi = min(nb + m, M - 1);
        const float* xr = X + (size_t)rowi * K;

        f32x4 acc[NT];
#pragma unroll
        for (int nt = 0; nt < NT; ++nt) acc[nt] = (f32x4){0.f, 0.f, 0.f, 0.f};

#pragma unroll
        for (int kc = 0; kc < KCH; ++kc) {
            float4 u0 = *(const float4*)&xr[kc * 32 + quad * 8];
            float4 u1 = *(const float4*)&xr[kc * 32 + quad * 8 + 4];
            f16x8 af;
            af[0] = (_Float16)u0.x;
            af[1] = (_Float16)u0.y;
            af[2] = (_Float16)u0.z;
            af[3] = (_Float16)u0.w;
            af[4] = (_Float16)u1.x;
            af[5] = (_Float16)u1.y;
            af[6] = (_Float16)u1.z;
            af[7] = (_Float16)u1.w;
#pragma unroll
            for (int nt = 0; nt < NT; ++nt)
                acc[nt] = __builtin_amdgcn_mfma_f32_16x16x32_f16(af, bf[kc][nt], acc[nt], 0, 0, 0);
        }

#pragma unroll
        for (int reg = 0; reg < 4; ++reg) {
            const int node = nb + quad * 4 + reg;
            if (node < M) {
                const float s = sdinv[node - bnode0];
#pragma unroll
                for (int nt = 0; nt < NT; ++nt) {
                    const int f = nt * 16 + m;
                    if (NOUT == NOUT_PAD || f < NOUT)
                        Hs[(size_t)node * OSTRIDE + f] = __float2half(acc[nt][reg] * s);
                }
            }
        }
    }
}

// ---------------- per-node wave gather, 8 row-slots x 8 chunk-lanes ----------------

__device__ inline void acc_row8(float (&acc)[8], uint4 u) {
    const __half2* hp = (const __half2*)&u;
#pragma unroll
    for (int k = 0; k < 4; ++k) {
        float2 f = __half22float2(hp[k]);
        acc[2 * k] += f.x;
        acc[2 * k + 1] += f.y;
    }
}

template <int FCHUNKS, bool RELU>  // FCHUNKS = valid 8-feature chunks (8 for 64, 5 for 40)
__global__ __launch_bounds__(256) void gather8_kernel(const int* __restrict__ rowptr,
                                                      const int* __restrict__ csr_src,
                                                      const float* __restrict__ dinv,
                                                      const __half* __restrict__ hs,
                                                      const float* __restrict__ b,
                                                      float* __restrict__ out, int n,
                                                      int outStride) {
    const int wave = (blockIdx.x * blockDim.x + threadIdx.x) >> 6;
    const int lane = threadIdx.x & 63;
    if (wave >= n) return;
    const int c = wave;
    const int g = lane >> 3;  // row slot
    const int q = lane & 7;   // 16B chunk within row
    const bool qv = q < FCHUNKS;

    const float dc = dinv[c];
    const int eBeg = rowptr[c];
    const int eEnd = rowptr[c + 1];

    float acc[8];
#pragma unroll
    for (int j = 0; j < 8; ++j) acc[j] = 0.f;

    if (g == 0 && qv) {
        uint4 u = *(const uint4*)&hs[(size_t)c * 64 + q * 8];
        acc_row8(acc, u);
    }

    for (int e = eBeg; e < eEnd; e += 16) {
        const int i0 = e + g;
        const int i1 = e + 8 + g;
        int r0 = (i0 < eEnd) ? csr_src[i0] : -1;
        int r1 = (i1 < eEnd) ? csr_src[i1] : -1;
        uint4 u0 = make_uint4(0, 0, 0, 0);
        uint4 u1 = make_uint4(0, 0, 0, 0);
        if (r0 >= 0 && qv) u0 = *(const uint4*)&hs[(size_t)r0 * 64 + q * 8];
        if (r1 >= 0 && qv) u1 = *(const uint4*)&hs[(size_t)r1 * 64 + q * 8];
        acc_row8(acc, u0);
        acc_row8(acc, u1);
    }

#pragma unroll
    for (int m = 8; m <= 32; m <<= 1)
#pragma unroll
        for (int j = 0; j < 8; ++j) acc[j] += __shfl_xor(acc[j], m, 64);

    if (g == 0 && qv) {
        float o[8];
#pragma unroll
        for (int j = 0; j < 8; ++j) {
            float v = fmaf(acc[j], dc, b[q * 8 + j]);
            o[j] = RELU ? fmaxf(v, 0.f) : v;
        }
        float* dst = &out[(size_t)c * outStride + q * 8];
        *(float4*)dst = make_float4(o[0], o[1], o[2], o[3]);
        *(float4*)(dst + 4) = make_float4(o[4], o[5], o[6], o[7]);
    }
}

// ---------------- launch ----------------

extern "C" void kernel_launch(void* const* d_in, const int* in_sizes, int n_in,
                              void* d_out, int out_size, void* d_ws, size_t ws_size,
                              hipStream_t stream) {
    const float* x = (const float*)d_in[0];
    const int* row = (const int*)d_in[1];
    const int* col = row + N_EDGES;
    const float* W1 = (const float*)d_in[2];
    const float* b1 = (const float*)d_in[3];
    const float* W2 = (const float*)d_in[4];
    const float* b2 = (const float*)d_in[5];
    float* out = (float*)d_out;

    const int N = N_NODES, E = N_EDGES;
    const int NB = (N + 1023) / 1024;

    char* p = (char*)d_ws;
    auto alloc = [&](size_t bytes) {
        char* q = p;
        p += (bytes + 15) & ~(size_t)15;
        return q;
    };
    int* cnt = (int*)alloc((size_t)N * 4);
    int* rowptr = (int*)alloc((size_t)(N + 1) * 4);
    int* csr_src = (int*)alloc((size_t)E * 4);
    int* blockSums = (int*)alloc((size_t)NB * 4);
    int* gcursor = (int*)alloc((size_t)NBK * 4);
    unsigned* bke = (unsigned*)alloc((size_t)NBK * BCAP * 4);
    float* dinv = (float*)alloc((size_t)N * 4);
    __half* h1s = (__half*)alloc((size_t)N * HIDDEN * 2);  // stride 64
    float* agg1 = (float*)alloc((size_t)N * HIDDEN * 4);
    __half* h2s = (__half*)alloc((size_t)N * HIDDEN * 2);  // 40 valid, stride 64

    // CSR build (bucket first; counts derived from buckets — no global atomics)
    init_gcursor_kernel<<<(NBK + 255) / 256, 256, 0, stream>>>(gcursor);
    bucket_kernel<<<(E + CHUNK - 1) / CHUNK, 256, 0, stream>>>(row, col, gcursor, bke, E);
    count_from_buckets_kernel<<<NBK, 256, 0, stream>>>(gcursor, bke, cnt, dinv, N);
    block_sum_kernel<<<NB, 256, 0, stream>>>(cnt, blockSums, N);
    scan_sums_kernel<<<1, 256, 0, stream>>>(blockSums, NB);
    scan_write_kernel<<<NB, 256, 0, stream>>>(cnt, blockSums, rowptr, N);
    csr_from_buckets_kernel<<<NBK, 256, 0, stream>>>(gcursor, bke, rowptr, csr_src, N);

    // layer 1
    gemm_mfma_kernel<N_FEAT, HIDDEN, HIDDEN, HIDDEN>
        <<<(N + 255) / 256, 256, 0, stream>>>(x, W1, dinv, h1s, N);
    gather8_kernel<8, true><<<(N + 3) / 4, 256, 0, stream>>>(rowptr, csr_src, dinv, h1s, b1,
                                                             agg1, N, HIDDEN);

    // layer 2 (NOUT 40 padded to 48 in-kernel; h2s rows stride 64, pad never read)
    gemm_mfma_kernel<HIDDEN, N_CLASSES, 48, HIDDEN>
        <<<(N + 255) / 256, 256, 0, stream>>>(agg1, W2, dinv, h2s, N);
    gather8_kernel<5, false><<<(N + 3) / 4, 256, 0, stream>>>(rowptr, csr_src, dinv, h2s, b2,
                                                              out, N, N_CLASSES);
}

// Round 9
// 250.646 us; speedup vs baseline: 7.8206x; 1.0164x over previous
//
#include <hip/hip_runtime.h>
#include <hip/hip_fp16.h>

#define N_NODES 100000
#define N_EDGES 1200000
#define N_FEAT 128
#define HIDDEN 64
#define N_CLASSES 40

// bucket sort parameters
#define BSHIFT 9
#define BMASK 511
#define BUCKET_NODES 512
#define NBK ((N_NODES + BUCKET_NODES - 1) / BUCKET_NODES)  // 196
#define BCAP 8192
#define CHUNK 2048

typedef _Float16 f16x8 __attribute__((ext_vector_type(8)));
typedef float f32x4 __attribute__((ext_vector_type(4)));

// ---- bucket pass: edges -> bucket-major packed array (block-aggregated writes) ----

__global__ void init_gcursor_kernel(int* __restrict__ gcursor) {
    int i = blockIdx.x * blockDim.x + threadIdx.x;
    if (i < NBK) gcursor[i] = i * BCAP;
}

__global__ __launch_bounds__(256) void bucket_kernel(const int* __restrict__ row,
                                                     const int* __restrict__ col,
                                                     int* __restrict__ gcursor,
                                                     unsigned* __restrict__ bke, int E) {
    __shared__ int hist[NBK];
    __shared__ int pfx[NBK];
    __shared__ int gbase[NBK];
    __shared__ int lcnt[NBK];
    __shared__ unsigned ord[CHUNK];
    __shared__ unsigned char obkt[CHUNK];

    const int t = threadIdx.x;
    const int e0 = blockIdx.x * CHUNK;
    const int nE = min(CHUNK, E - e0);

    for (int i = t; i < NBK; i += 256) {
        hist[i] = 0;
        lcnt[i] = 0;
    }
    __syncthreads();

    for (int i = t; i < nE; i += 256) atomicAdd(&hist[col[e0 + i] >> BSHIFT], 1);
    __syncthreads();

    int v = (t < NBK) ? hist[t] : 0;
    if (t < NBK) pfx[t] = v;
    __syncthreads();
    for (int d = 1; d < 256; d <<= 1) {
        int add = (t >= d && t < NBK) ? pfx[t - d] : 0;
        __syncthreads();
        if (t < NBK) pfx[t] += add;
        __syncthreads();
    }
    if (t < NBK) {
        pfx[t] -= v;  // exclusive
        gbase[t] = (v > 0) ? atomicAdd(&gcursor[t], v) : 0;
    }
    __syncthreads();

    for (int i = t; i < nE; i += 256) {
        int r = row[e0 + i];
        int c = col[e0 + i];
        int b = c >> BSHIFT;
        int pos = pfx[b] + atomicAdd(&lcnt[b], 1);
        ord[pos] = ((unsigned)r << BSHIFT) | (unsigned)(c & BMASK);
        obkt[pos] = (unsigned char)b;
    }
    __syncthreads();

    for (int i = t; i < nE; i += 256) {
        int b = obkt[i];
        bke[(size_t)gbase[b] + (i - pfx[b])] = ord[i];
    }
}

// ---- per-bucket totals (from gcursor) -> exclusive bucket bases ----

__global__ __launch_bounds__(256) void scan_sums_kernel(const int* __restrict__ gcursor,
                                                        int* __restrict__ bucketBase) {
    __shared__ int lds[256];
    const int t = threadIdx.x;
    const int v = (t < NBK) ? (gcursor[t] - t * BCAP) : 0;
    lds[t] = v;
    __syncthreads();
    for (int d = 1; d < 256; d <<= 1) {
        int add = (t >= d) ? lds[t - d] : 0;
        __syncthreads();
        lds[t] += add;
        __syncthreads();
    }
    if (t < NBK) bucketBase[t] = lds[t] - v;  // exclusive
}

// ---- fused per-bucket: hist -> rowptr + dinv -> scatter into contiguous CSR ----

__global__ __launch_bounds__(256) void place_kernel(const int* __restrict__ gcursor,
                                                    const unsigned* __restrict__ bke,
                                                    const int* __restrict__ bucketBase,
                                                    int* __restrict__ rowptr,
                                                    float* __restrict__ dinv,
                                                    int* __restrict__ csr_src, int n) {
    __shared__ int hist[BUCKET_NODES];
    __shared__ int cur[BUCKET_NODES];
    __shared__ int tsum[256];

    const int b = blockIdx.x, t = threadIdx.x;
    const int node0 = b << BSHIFT;
    const int nNodes = min(BUCKET_NODES, n - node0);

    hist[t] = 0;
    hist[t + 256] = 0;
    __syncthreads();

    const int nb = gcursor[b] - b * BCAP;
    const unsigned* src = bke + (size_t)b * BCAP;
    for (int i = t; i < nb; i += 256) atomicAdd(&hist[src[i] & BMASK], 1);
    __syncthreads();

    // 512-wide exclusive scan: thread t owns elements 2t, 2t+1
    const int c0 = hist[2 * t];
    const int c1 = hist[2 * t + 1];
    const int s = c0 + c1;
    tsum[t] = s;
    __syncthreads();
    for (int d = 1; d < 256; d <<= 1) {
        int add = (t >= d) ? tsum[t - d] : 0;
        __syncthreads();
        tsum[t] += add;
        __syncthreads();
    }
    const int base = bucketBase[b];
    const int e0 = base + tsum[t] - s;  // exclusive prefix of elem 2t
    const int e1 = e0 + c0;

    cur[2 * t] = e0;
    cur[2 * t + 1] = e1;
    if (2 * t < nNodes) {
        rowptr[node0 + 2 * t] = e0;
        dinv[node0 + 2 * t] = rsqrtf((float)(c0 + 1));
    }
    if (2 * t + 1 < nNodes) {
        rowptr[node0 + 2 * t + 1] = e1;
        dinv[node0 + 2 * t + 1] = rsqrtf((float)(c1 + 1));
    }
    if (t == 0 && node0 + nNodes == n) rowptr[n] = N_EDGES;
    __syncthreads();

    for (int i = t; i < nb; i += 256) {
        unsigned p = src[i];
        int pos = atomicAdd(&cur[p & BMASK], 1);
        csr_src[pos] = (int)(p >> BSHIFT);
    }
}

// ---------------- MFMA GEMM with scaled-fp16 epilogue ----------------
// Hs[node, f<NOUT] = fp16( (X @ W)[node,f] * dinv[node] ), row stride OSTRIDE halves.
// v_mfma_f32_16x16x32_f16 layouts (m89/m120 verified):
//   A[m=lane&15][k=quad*8+j], B[k=quad*8+j][n=lane&15], C: col=lane&15,row=quad*4+reg.

template <int K, int NOUT, int NOUT_PAD, int OSTRIDE>
__global__ __launch_bounds__(256) void gemm_mfma_kernel(const float* __restrict__ X,
                                                        const float* __restrict__ W,
                                                        const float* __restrict__ dinv,
                                                        __half* __restrict__ Hs, int M) {
    constexpr int KCH = K / 32;
    constexpr int NT = NOUT_PAD / 16;
    constexpr int WPITCH = NOUT_PAD + 2;

    __shared__ _Float16 wh[K * WPITCH];
    __shared__ float sdinv[256];

    const int tid = threadIdx.x;
    const int bnode0 = blockIdx.x * 256;

    for (int i = tid; i < K * NOUT_PAD; i += 256) {
        int k = i / NOUT_PAD, n = i % NOUT_PAD;
        wh[k * WPITCH + n] = (n < NOUT) ? (_Float16)W[k * NOUT + n] : (_Float16)0.0f;
    }
    {
        int node = bnode0 + tid;
        sdinv[tid] = (node < M) ? dinv[node] : 0.f;
    }
    __syncthreads();

    const int wid = tid >> 6;
    const int lane = tid & 63;
    const int m = lane & 15;
    const int quad = lane >> 4;

    f16x8 bf[KCH][NT];
#pragma unroll
    for (int kc = 0; kc < KCH; ++kc)
#pragma unroll
        for (int nt = 0; nt < NT; ++nt)
#pragma unroll
            for (int j = 0; j < 8; ++j)
                bf[kc][nt][j] = wh[(kc * 32 + quad * 8 + j) * WPITCH + nt * 16 + m];

    for (int nt4 = 0; nt4 < 4; ++nt4) {
        const int nb = bnode0 + wid * 64 + nt4 * 16;
        if (nb >= M) break;
        const int rowi = min(nb + m, M - 1);
        const float* xr = X + (size_t)rowi * K;

        f32x4 acc[NT];
#pragma unroll
        for (int nt = 0; nt < NT; ++nt) acc[nt] = (f32x4){0.f, 0.f, 0.f, 0.f};

#pragma unroll
        for (int kc = 0; kc < KCH; ++kc) {
            float4 u0 = *(const float4*)&xr[kc * 32 + quad * 8];
            float4 u1 = *(const float4*)&xr[kc * 32 + quad * 8 + 4];
            f16x8 af;
            af[0] = (_Float16)u0.x;
            af[1] = (_Float16)u0.y;
            af[2] = (_Float16)u0.z;
            af[3] = (_Float16)u0.w;
            af[4] = (_Float16)u1.x;
            af[5] = (_Float16)u1.y;
            af[6] = (_Float16)u1.z;
            af[7] = (_Float16)u1.w;
#pragma unroll
            for (int nt = 0; nt < NT; ++nt)
                acc[nt] = __builtin_amdgcn_mfma_f32_16x16x32_f16(af, bf[kc][nt], acc[nt], 0, 0, 0);
        }

#pragma unroll
        for (int reg = 0; reg < 4; ++reg) {
            const int node = nb + quad * 4 + reg;
            if (node < M) {
                const float s = sdinv[node - bnode0];
#pragma unroll
                for (int nt = 0; nt < NT; ++nt) {
                    const int f = nt * 16 + m;
                    if (NOUT == NOUT_PAD || f < NOUT)
                        Hs[(size_t)node * OSTRIDE + f] = __float2half(acc[nt][reg] * s);
                }
            }
        }
    }
}

// ---------------- per-node wave gather, 8 row-slots x 8 chunk-lanes ----------------

__device__ inline void acc_row8(float (&acc)[8], uint4 u) {
    const __half2* hp = (const __half2*)&u;
#pragma unroll
    for (int k = 0; k < 4; ++k) {
        float2 f = __half22float2(hp[k]);
        acc[2 * k] += f.x;
        acc[2 * k + 1] += f.y;
    }
}

template <int FCHUNKS, bool RELU>  // FCHUNKS = valid 8-feature chunks (8 for 64, 5 for 40)
__global__ __launch_bounds__(256) void gather8_kernel(const int* __restrict__ rowptr,
                                                      const int* __restrict__ csr_src,
                                                      const float* __restrict__ dinv,
                                                      const __half* __restrict__ hs,
                                                      const float* __restrict__ b,
                                                      float* __restrict__ out, int n,
                                                      int outStride) {
    const int wave = (blockIdx.x * blockDim.x + threadIdx.x) >> 6;
    const int lane = threadIdx.x & 63;
    if (wave >= n) return;
    const int c = wave;
    const int g = lane >> 3;  // row slot
    const int q = lane & 7;   // 16B chunk within row
    const bool qv = q < FCHUNKS;

    const float dc = dinv[c];
    const int eBeg = rowptr[c];
    const int eEnd = rowptr[c + 1];

    float acc[8];
#pragma unroll
    for (int j = 0; j < 8; ++j) acc[j] = 0.f;

    if (g == 0 && qv) {
        uint4 u = *(const uint4*)&hs[(size_t)c * 64 + q * 8];
        acc_row8(acc, u);
    }

    for (int e = eBeg; e < eEnd; e += 16) {
        const int i0 = e + g;
        const int i1 = e + 8 + g;
        int r0 = (i0 < eEnd) ? csr_src[i0] : -1;
        int r1 = (i1 < eEnd) ? csr_src[i1] : -1;
        uint4 u0 = make_uint4(0, 0, 0, 0);
        uint4 u1 = make_uint4(0, 0, 0, 0);
        if (r0 >= 0 && qv) u0 = *(const uint4*)&hs[(size_t)r0 * 64 + q * 8];
        if (r1 >= 0 && qv) u1 = *(const uint4*)&hs[(size_t)r1 * 64 + q * 8];
        acc_row8(acc, u0);
        acc_row8(acc, u1);
    }

#pragma unroll
    for (int m = 8; m <= 32; m <<= 1)
#pragma unroll
        for (int j = 0; j < 8; ++j) acc[j] += __shfl_xor(acc[j], m, 64);

    if (g == 0 && qv) {
        float o[8];
#pragma unroll
        for (int j = 0; j < 8; ++j) {
            float v = fmaf(acc[j], dc, b[q * 8 + j]);
            o[j] = RELU ? fmaxf(v, 0.f) : v;
        }
        float* dst = &out[(size_t)c * outStride + q * 8];
        *(float4*)dst = make_float4(o[0], o[1], o[2], o[3]);
        *(float4*)(dst + 4) = make_float4(o[4], o[5], o[6], o[7]);
    }
}

// ---------------- launch ----------------

extern "C" void kernel_launch(void* const* d_in, const int* in_sizes, int n_in,
                              void* d_out, int out_size, void* d_ws, size_t ws_size,
                              hipStream_t stream) {
    const float* x = (const float*)d_in[0];
    const int* row = (const int*)d_in[1];
    const int* col = row + N_EDGES;
    const float* W1 = (const float*)d_in[2];
    const float* b1 = (const float*)d_in[3];
    const float* W2 = (const float*)d_in[4];
    const float* b2 = (const float*)d_in[5];
    float* out = (float*)d_out;

    const int N = N_NODES, E = N_EDGES;

    char* p = (char*)d_ws;
    auto alloc = [&](size_t bytes) {
        char* q = p;
        p += (bytes + 15) & ~(size_t)15;
        return q;
    };
    int* rowptr = (int*)alloc((size_t)(N + 1) * 4);
    int* csr_src = (int*)alloc((size_t)E * 4);
    int* gcursor = (int*)alloc((size_t)NBK * 4);
    int* bucketBase = (int*)alloc((size_t)NBK * 4);
    unsigned* bke = (unsigned*)alloc((size_t)NBK * BCAP * 4);
    float* dinv = (float*)alloc((size_t)N * 4);
    __half* h1s = (__half*)alloc((size_t)N * HIDDEN * 2);  // stride 64
    float* agg1 = (float*)alloc((size_t)N * HIDDEN * 4);
    __half* h2s = (__half*)alloc((size_t)N * HIDDEN * 2);  // 40 valid, stride 64

    // CSR build: 4 kernels, no global atomics on node-granularity data
    init_gcursor_kernel<<<(NBK + 255) / 256, 256, 0, stream>>>(gcursor);
    bucket_kernel<<<(E + CHUNK - 1) / CHUNK, 256, 0, stream>>>(row, col, gcursor, bke, E);
    scan_sums_kernel<<<1, 256, 0, stream>>>(gcursor, bucketBase);
    place_kernel<<<NBK, 256, 0, stream>>>(gcursor, bke, bucketBase, rowptr, dinv, csr_src, N);

    // layer 1
    gemm_mfma_kernel<N_FEAT, HIDDEN, HIDDEN, HIDDEN>
        <<<(N + 255) / 256, 256, 0, stream>>>(x, W1, dinv, h1s, N);
    gather8_kernel<8, true><<<(N + 3) / 4, 256, 0, stream>>>(rowptr, csr_src, dinv, h1s, b1,
                                                             agg1, N, HIDDEN);

    // layer 2 (NOUT 40 padded to 48 in-kernel; h2s rows stride 64, pad never read)
    gemm_mfma_kernel<HIDDEN, N_CLASSES, 48, HIDDEN>
        <<<(N + 255) / 256, 256, 0, stream>>>(agg1, W2, dinv, h2s, N);
    gather8_kernel<5, false><<<(N + 3) / 4, 256, 0, stream>>>(rowptr, csr_src, dinv, h2s, b2,
                                                              out, N, N_CLASSES);
}

// Round 10
// 246.717 us; speedup vs baseline: 7.9452x; 1.0159x over previous
//
#include <hip/hip_runtime.h>
#include <hip/hip_fp16.h>
#include <type_traits>

#define N_NODES 100000
#define N_EDGES 1200000
#define N_FEAT 128
#define HIDDEN 64
#define N_CLASSES 40

// bucket sort parameters
#define BSHIFT 9
#define BMASK 511
#define BUCKET_NODES 512
#define NBK ((N_NODES + BUCKET_NODES - 1) / BUCKET_NODES)  // 196
#define BCAP 8192
#define CHUNK 2048

typedef _Float16 f16x8 __attribute__((ext_vector_type(8)));
typedef float f32x4 __attribute__((ext_vector_type(4)));

// ---- bucket pass: edges -> bucket-major packed array (block-aggregated writes) ----

__global__ void init_gcursor_kernel(int* __restrict__ gcursor) {
    int i = blockIdx.x * blockDim.x + threadIdx.x;
    if (i < NBK) gcursor[i] = i * BCAP;
}

__global__ __launch_bounds__(256) void bucket_kernel(const int* __restrict__ row,
                                                     const int* __restrict__ col,
                                                     int* __restrict__ gcursor,
                                                     unsigned* __restrict__ bke, int E) {
    __shared__ int hist[NBK];
    __shared__ int pfx[NBK];
    __shared__ int gbase[NBK];
    __shared__ int lcnt[NBK];
    __shared__ unsigned ord[CHUNK];
    __shared__ unsigned char obkt[CHUNK];

    const int t = threadIdx.x;
    const int e0 = blockIdx.x * CHUNK;
    const int nE = min(CHUNK, E - e0);

    for (int i = t; i < NBK; i += 256) {
        hist[i] = 0;
        lcnt[i] = 0;
    }
    __syncthreads();

    for (int i = t; i < nE; i += 256) atomicAdd(&hist[col[e0 + i] >> BSHIFT], 1);
    __syncthreads();

    int v = (t < NBK) ? hist[t] : 0;
    if (t < NBK) pfx[t] = v;
    __syncthreads();
    for (int d = 1; d < 256; d <<= 1) {
        int add = (t >= d && t < NBK) ? pfx[t - d] : 0;
        __syncthreads();
        if (t < NBK) pfx[t] += add;
        __syncthreads();
    }
    if (t < NBK) {
        pfx[t] -= v;  // exclusive
        gbase[t] = (v > 0) ? atomicAdd(&gcursor[t], v) : 0;
    }
    __syncthreads();

    for (int i = t; i < nE; i += 256) {
        int r = row[e0 + i];
        int c = col[e0 + i];
        int b = c >> BSHIFT;
        int pos = pfx[b] + atomicAdd(&lcnt[b], 1);
        ord[pos] = ((unsigned)r << BSHIFT) | (unsigned)(c & BMASK);
        obkt[pos] = (unsigned char)b;
    }
    __syncthreads();

    for (int i = t; i < nE; i += 256) {
        int b = obkt[i];
        bke[(size_t)gbase[b] + (i - pfx[b])] = ord[i];
    }
}

// ---- per-bucket totals (from gcursor) -> exclusive bucket bases ----

__global__ __launch_bounds__(256) void scan_sums_kernel(const int* __restrict__ gcursor,
                                                        int* __restrict__ bucketBase) {
    __shared__ int lds[256];
    const int t = threadIdx.x;
    const int v = (t < NBK) ? (gcursor[t] - t * BCAP) : 0;
    lds[t] = v;
    __syncthreads();
    for (int d = 1; d < 256; d <<= 1) {
        int add = (t >= d) ? lds[t - d] : 0;
        __syncthreads();
        lds[t] += add;
        __syncthreads();
    }
    if (t < NBK) bucketBase[t] = lds[t] - v;  // exclusive
}

// ---- fused per-bucket: hist -> rowptr + dinv -> scatter into contiguous CSR ----

__global__ __launch_bounds__(256) void place_kernel(const int* __restrict__ gcursor,
                                                    const unsigned* __restrict__ bke,
                                                    const int* __restrict__ bucketBase,
                                                    int* __restrict__ rowptr,
                                                    float* __restrict__ dinv,
                                                    int* __restrict__ csr_src, int n) {
    __shared__ int hist[BUCKET_NODES];
    __shared__ int cur[BUCKET_NODES];
    __shared__ int tsum[256];

    const int b = blockIdx.x, t = threadIdx.x;
    const int node0 = b << BSHIFT;
    const int nNodes = min(BUCKET_NODES, n - node0);

    hist[t] = 0;
    hist[t + 256] = 0;
    __syncthreads();

    const int nb = gcursor[b] - b * BCAP;
    const unsigned* src = bke + (size_t)b * BCAP;
    for (int i = t; i < nb; i += 256) atomicAdd(&hist[src[i] & BMASK], 1);
    __syncthreads();

    // 512-wide exclusive scan: thread t owns elements 2t, 2t+1
    const int c0 = hist[2 * t];
    const int c1 = hist[2 * t + 1];
    const int s = c0 + c1;
    tsum[t] = s;
    __syncthreads();
    for (int d = 1; d < 256; d <<= 1) {
        int add = (t >= d) ? tsum[t - d] : 0;
        __syncthreads();
        tsum[t] += add;
        __syncthreads();
    }
    const int base = bucketBase[b];
    const int e0 = base + tsum[t] - s;
    const int e1 = e0 + c0;

    cur[2 * t] = e0;
    cur[2 * t + 1] = e1;
    if (2 * t < nNodes) {
        rowptr[node0 + 2 * t] = e0;
        dinv[node0 + 2 * t] = rsqrtf((float)(c0 + 1));
    }
    if (2 * t + 1 < nNodes) {
        rowptr[node0 + 2 * t + 1] = e1;
        dinv[node0 + 2 * t + 1] = rsqrtf((float)(c1 + 1));
    }
    if (t == 0 && node0 + nNodes == n) rowptr[n] = N_EDGES;
    __syncthreads();

    for (int i = t; i < nb; i += 256) {
        unsigned p = src[i];
        int pos = atomicAdd(&cur[p & BMASK], 1);
        csr_src[pos] = (int)(p >> BSHIFT);
    }
}

// ---------------- MFMA GEMM with scaled-fp16 epilogue ----------------
// Hs[node, f<NOUT] = fp16( (X @ W)[node,f] * dinv[node] ), row stride OSTRIDE halves.
// XT = float (layer 1, cvt in-flight) or _Float16 (layer 2, native A-frags).
// v_mfma_f32_16x16x32_f16 layouts (m89/m120 verified):
//   A[m=lane&15][k=quad*8+j], B[k=quad*8+j][n=lane&15], C: col=lane&15,row=quad*4+reg.

template <typename XT, int K, int XSTRIDE, int NOUT, int NOUT_PAD, int OSTRIDE>
__global__ __launch_bounds__(256) void gemm_mfma_kernel(const XT* __restrict__ X,
                                                        const float* __restrict__ W,
                                                        const float* __restrict__ dinv,
                                                        __half* __restrict__ Hs, int M) {
    constexpr int KCH = K / 32;
    constexpr int NT = NOUT_PAD / 16;
    constexpr int WPITCH = NOUT_PAD + 2;

    __shared__ _Float16 wh[K * WPITCH];
    __shared__ float sdinv[256];

    const int tid = threadIdx.x;
    const int bnode0 = blockIdx.x * 256;

    for (int i = tid; i < K * NOUT_PAD; i += 256) {
        int k = i / NOUT_PAD, n = i % NOUT_PAD;
        wh[k * WPITCH + n] = (n < NOUT) ? (_Float16)W[k * NOUT + n] : (_Float16)0.0f;
    }
    {
        int node = bnode0 + tid;
        sdinv[tid] = (node < M) ? dinv[node] : 0.f;
    }
    __syncthreads();

    const int wid = tid >> 6;
    const int lane = tid & 63;
    const int m = lane & 15;
    const int quad = lane >> 4;

    f16x8 bf[KCH][NT];
#pragma unroll
    for (int kc = 0; kc < KCH; ++kc)
#pragma unroll
        for (int nt = 0; nt < NT; ++nt)
#pragma unroll
            for (int j = 0; j < 8; ++j)
                bf[kc][nt][j] = wh[(kc * 32 + quad * 8 + j) * WPITCH + nt * 16 + m];

    for (int nt4 = 0; nt4 < 4; ++nt4) {
        const int nb = bnode0 + wid * 64 + nt4 * 16;
        if (nb >= M) break;
        const int rowi = min(nb + m, M - 1);
        const XT* xr = X + (size_t)rowi * XSTRIDE;

        f32x4 acc[NT];
#pragma unroll
        for (int nt = 0; nt < NT; ++nt) acc[nt] = (f32x4){0.f, 0.f, 0.f, 0.f};

#pragma unroll
        for (int kc = 0; kc < KCH; ++kc) {
            f16x8 af;
            if constexpr (std::is_same<XT, float>::value) {
                float4 u0 = *(const float4*)&xr[kc * 32 + quad * 8];
                float4 u1 = *(const float4*)&xr[kc * 32 + quad * 8 + 4];
                af[0] = (_Float16)u0.x;
                af[1] = (_Float16)u0.y;
                af[2] = (_Float16)u0.z;
                af[3] = (_Float16)u0.w;
                af[4] = (_Float16)u1.x;
                af[5] = (_Float16)u1.y;
                af[6] = (_Float16)u1.z;
                af[7] = (_Float16)u1.w;
            } else {
                af = *(const f16x8*)&xr[kc * 32 + quad * 8];
            }
#pragma unroll
            for (int nt = 0; nt < NT; ++nt)
                acc[nt] = __builtin_amdgcn_mfma_f32_16x16x32_f16(af, bf[kc][nt], acc[nt], 0, 0, 0);
        }

#pragma unroll
        for (int reg = 0; reg < 4; ++reg) {
            const int node = nb + quad * 4 + reg;
            if (node < M) {
                const float s = sdinv[node - bnode0];
#pragma unroll
                for (int nt = 0; nt < NT; ++nt) {
                    const int f = nt * 16 + m;
                    if (NOUT == NOUT_PAD || f < NOUT)
                        Hs[(size_t)node * OSTRIDE + f] = __float2half(acc[nt][reg] * s);
                }
            }
        }
    }
}

// ---------------- per-node wave gather, 8 row-slots x 8 chunk-lanes ----------------
// hs rows: stride HSTRIDE halves (64 for layer1, 40 packed for layer2).
// OutT = __half (agg1, fp16 store) or float (final output).

__device__ inline void acc_row8(float (&acc)[8], uint4 u) {
    const __half2* hp = (const __half2*)&u;
#pragma unroll
    for (int k = 0; k < 4; ++k) {
        float2 f = __half22float2(hp[k]);
        acc[2 * k] += f.x;
        acc[2 * k + 1] += f.y;
    }
}

template <typename OutT, int FCHUNKS, int HSTRIDE, int OUTSTRIDE, bool RELU>
__global__ __launch_bounds__(256) void gather8_kernel(const int* __restrict__ rowptr,
                                                      const int* __restrict__ csr_src,
                                                      const float* __restrict__ dinv,
                                                      const __half* __restrict__ hs,
                                                      const float* __restrict__ b,
                                                      OutT* __restrict__ out, int n) {
    const int wave = (blockIdx.x * blockDim.x + threadIdx.x) >> 6;
    const int lane = threadIdx.x & 63;
    if (wave >= n) return;
    const int c = wave;
    const int g = lane >> 3;  // row slot
    const int q = lane & 7;   // 16B chunk within row
    const bool qv = q < FCHUNKS;

    const float dc = dinv[c];
    const int eBeg = rowptr[c];
    const int eEnd = rowptr[c + 1];

    float acc[8];
#pragma unroll
    for (int j = 0; j < 8; ++j) acc[j] = 0.f;

    if (g == 0 && qv) {
        uint4 u = *(const uint4*)&hs[(size_t)c * HSTRIDE + q * 8];
        acc_row8(acc, u);
    }

    for (int e = eBeg; e < eEnd; e += 16) {
        const int i0 = e + g;
        const int i1 = e + 8 + g;
        int r0 = (i0 < eEnd) ? csr_src[i0] : -1;
        int r1 = (i1 < eEnd) ? csr_src[i1] : -1;
        uint4 u0 = make_uint4(0, 0, 0, 0);
        uint4 u1 = make_uint4(0, 0, 0, 0);
        if (r0 >= 0 && qv) u0 = *(const uint4*)&hs[(size_t)r0 * HSTRIDE + q * 8];
        if (r1 >= 0 && qv) u1 = *(const uint4*)&hs[(size_t)r1 * HSTRIDE + q * 8];
        acc_row8(acc, u0);
        acc_row8(acc, u1);
    }

#pragma unroll
    for (int m = 8; m <= 32; m <<= 1)
#pragma unroll
        for (int j = 0; j < 8; ++j) acc[j] += __shfl_xor(acc[j], m, 64);

    if (g == 0 && qv) {
        float o[8];
#pragma unroll
        for (int j = 0; j < 8; ++j) {
            float v = fmaf(acc[j], dc, b[q * 8 + j]);
            o[j] = RELU ? fmaxf(v, 0.f) : v;
        }
        if constexpr (std::is_same<OutT, float>::value) {
            float* dst = &out[(size_t)c * OUTSTRIDE + q * 8];
            *(float4*)dst = make_float4(o[0], o[1], o[2], o[3]);
            *(float4*)(dst + 4) = make_float4(o[4], o[5], o[6], o[7]);
        } else {
            __half2 pk[4];
#pragma unroll
            for (int k = 0; k < 4; ++k) pk[k] = __floats2half2_rn(o[2 * k], o[2 * k + 1]);
            *(uint4*)&out[(size_t)c * OUTSTRIDE + q * 8] = *(uint4*)pk;
        }
    }
}

// ---------------- launch ----------------

extern "C" void kernel_launch(void* const* d_in, const int* in_sizes, int n_in,
                              void* d_out, int out_size, void* d_ws, size_t ws_size,
                              hipStream_t stream) {
    const float* x = (const float*)d_in[0];
    const int* row = (const int*)d_in[1];
    const int* col = row + N_EDGES;
    const float* W1 = (const float*)d_in[2];
    const float* b1 = (const float*)d_in[3];
    const float* W2 = (const float*)d_in[4];
    const float* b2 = (const float*)d_in[5];
    float* out = (float*)d_out;

    const int N = N_NODES, E = N_EDGES;

    char* p = (char*)d_ws;
    auto alloc = [&](size_t bytes) {
        char* q = p;
        p += (bytes + 15) & ~(size_t)15;
        return q;
    };
    int* rowptr = (int*)alloc((size_t)(N + 1) * 4);
    int* csr_src = (int*)alloc((size_t)E * 4);
    int* gcursor = (int*)alloc((size_t)NBK * 4);
    int* bucketBase = (int*)alloc((size_t)NBK * 4);
    unsigned* bke = (unsigned*)alloc((size_t)NBK * BCAP * 4);
    float* dinv = (float*)alloc((size_t)N * 4);
    __half* h1s = (__half*)alloc((size_t)N * HIDDEN * 2);     // stride 64 halves
    __half* agg1h = (__half*)alloc((size_t)N * HIDDEN * 2);   // fp16 agg, stride 64
    __half* h2s = (__half*)alloc((size_t)N * N_CLASSES * 2);  // packed stride 40 halves

    // CSR build: 4 kernels, no global atomics on node-granularity data
    init_gcursor_kernel<<<(NBK + 255) / 256, 256, 0, stream>>>(gcursor);
    bucket_kernel<<<(E + CHUNK - 1) / CHUNK, 256, 0, stream>>>(row, col, gcursor, bke, E);
    scan_sums_kernel<<<1, 256, 0, stream>>>(gcursor, bucketBase);
    place_kernel<<<NBK, 256, 0, stream>>>(gcursor, bke, bucketBase, rowptr, dinv, csr_src, N);

    // layer 1: fp32 X -> fp16 h1s (stride 64); gather -> fp16 agg1h
    gemm_mfma_kernel<float, N_FEAT, N_FEAT, HIDDEN, HIDDEN, HIDDEN>
        <<<(N + 255) / 256, 256, 0, stream>>>(x, W1, dinv, h1s, N);
    gather8_kernel<__half, 8, HIDDEN, HIDDEN, true>
        <<<(N + 3) / 4, 256, 0, stream>>>(rowptr, csr_src, dinv, h1s, b1, agg1h, N);

    // layer 2: fp16 agg1h -> packed h2s (stride 40); gather -> fp32 out
    gemm_mfma_kernel<_Float16, HIDDEN, HIDDEN, N_CLASSES, 48, N_CLASSES>
        <<<(N + 255) / 256, 256, 0, stream>>>((const _Float16*)agg1h, W2, dinv, h2s, N);
    gather8_kernel<float, 5, N_CLASSES, N_CLASSES, false>
        <<<(N + 3) / 4, 256, 0, stream>>>(rowptr, csr_src, dinv, h2s, b2, out, N);
}

// Round 11
// 236.673 us; speedup vs baseline: 8.2823x; 1.0424x over previous
//
#include <hip/hip_runtime.h>
#include <hip/hip_fp16.h>
#include <type_traits>

#define N_NODES 100000
#define N_EDGES 1200000
#define N_FEAT 128
#define HIDDEN 64
#define N_CLASSES 40

// bucket sort parameters
#define BSHIFT 9
#define BMASK 511
#define BUCKET_NODES 512
#define NBK ((N_NODES + BUCKET_NODES - 1) / BUCKET_NODES)  // 196
#define BCAP 8192
#define CHUNK 2048

typedef _Float16 f16x8 __attribute__((ext_vector_type(8)));
typedef float f32x4 __attribute__((ext_vector_type(4)));

// ---- bucket pass: edges -> bucket-major packed array (block-aggregated writes) ----
// gcursor is zero-initialized (memset); cursors are relative, so gcursor[b] ends
// up holding bucket b's total count.

__global__ __launch_bounds__(256) void bucket_kernel(const int* __restrict__ row,
                                                     const int* __restrict__ col,
                                                     int* __restrict__ gcursor,
                                                     unsigned* __restrict__ bke, int E) {
    __shared__ int hist[NBK];
    __shared__ int pfx[NBK];
    __shared__ int gbase[NBK];
    __shared__ int lcnt[NBK];
    __shared__ unsigned ord[CHUNK];
    __shared__ unsigned char obkt[CHUNK];

    const int t = threadIdx.x;
    const int e0 = blockIdx.x * CHUNK;
    const int nE = min(CHUNK, E - e0);

    for (int i = t; i < NBK; i += 256) {
        hist[i] = 0;
        lcnt[i] = 0;
    }
    __syncthreads();

    for (int i = t; i < nE; i += 256) atomicAdd(&hist[col[e0 + i] >> BSHIFT], 1);
    __syncthreads();

    int v = (t < NBK) ? hist[t] : 0;
    if (t < NBK) pfx[t] = v;
    __syncthreads();
    for (int d = 1; d < 256; d <<= 1) {
        int add = (t >= d && t < NBK) ? pfx[t - d] : 0;
        __syncthreads();
        if (t < NBK) pfx[t] += add;
        __syncthreads();
    }
    if (t < NBK) {
        pfx[t] -= v;  // exclusive
        gbase[t] = t * BCAP + ((v > 0) ? atomicAdd(&gcursor[t], v) : 0);
    }
    __syncthreads();

    for (int i = t; i < nE; i += 256) {
        int r = row[e0 + i];
        int c = col[e0 + i];
        int b = c >> BSHIFT;
        int pos = pfx[b] + atomicAdd(&lcnt[b], 1);
        ord[pos] = ((unsigned)r << BSHIFT) | (unsigned)(c & BMASK);
        obkt[pos] = (unsigned char)b;
    }
    __syncthreads();

    for (int i = t; i < nE; i += 256) {
        int b = obkt[i];
        bke[(size_t)gbase[b] + (i - pfx[b])] = ord[i];
    }
}

// ---- fused per-bucket: bucketBase scan + hist -> rowptr + dinv -> scatter CSR ----

__global__ __launch_bounds__(256) void place_kernel(const int* __restrict__ gcursor,
                                                    const unsigned* __restrict__ bke,
                                                    int* __restrict__ rowptr,
                                                    float* __restrict__ dinv,
                                                    int* __restrict__ csr_src, int n) {
    __shared__ int hist[BUCKET_NODES];
    __shared__ int cur[BUCKET_NODES];
    __shared__ int tsum[256];

    const int b = blockIdx.x, t = threadIdx.x;
    const int node0 = b << BSHIFT;
    const int nNodes = min(BUCKET_NODES, n - node0);

    // bucket base: exclusive prefix over the 196 bucket counts (gcursor holds counts)
    const int myCnt = (t < NBK) ? gcursor[t] : 0;
    tsum[t] = myCnt;
    __syncthreads();
    for (int d = 1; d < 256; d <<= 1) {
        int add = (t >= d) ? tsum[t - d] : 0;
        __syncthreads();
        tsum[t] += add;
        __syncthreads();
    }
    const int base = tsum[b] - gcursor[b];  // exclusive prefix at b
    const int nb = gcursor[b];
    __syncthreads();

    hist[t] = 0;
    hist[t + 256] = 0;
    __syncthreads();

    const unsigned* src = bke + (size_t)b * BCAP;
    for (int i = t; i < nb; i += 256) atomicAdd(&hist[src[i] & BMASK], 1);
    __syncthreads();

    // 512-wide exclusive scan: thread t owns elements 2t, 2t+1
    const int c0 = hist[2 * t];
    const int c1 = hist[2 * t + 1];
    const int s = c0 + c1;
    tsum[t] = s;
    __syncthreads();
    for (int d = 1; d < 256; d <<= 1) {
        int add = (t >= d) ? tsum[t - d] : 0;
        __syncthreads();
        tsum[t] += add;
        __syncthreads();
    }
    const int e0 = base + tsum[t] - s;
    const int e1 = e0 + c0;

    cur[2 * t] = e0;
    cur[2 * t + 1] = e1;
    if (2 * t < nNodes) {
        rowptr[node0 + 2 * t] = e0;
        dinv[node0 + 2 * t] = rsqrtf((float)(c0 + 1));
    }
    if (2 * t + 1 < nNodes) {
        rowptr[node0 + 2 * t + 1] = e1;
        dinv[node0 + 2 * t + 1] = rsqrtf((float)(c1 + 1));
    }
    if (t == 0 && node0 + nNodes == n) rowptr[n] = N_EDGES;
    __syncthreads();

    for (int i = t; i < nb; i += 256) {
        unsigned p = src[i];
        int pos = atomicAdd(&cur[p & BMASK], 1);
        csr_src[pos] = (int)(p >> BSHIFT);
    }
}

// ---------------- MFMA GEMM with scaled-fp16 epilogue ----------------
// Hs[node, f<NOUT] = fp16( (X @ W)[node,f] * dinv[node] ), row stride OSTRIDE halves.
// XT = float (layer 1, cvt in-flight) or _Float16 (layer 2, native A-frags).
// v_mfma_f32_16x16x32_f16 layouts (m89/m120 verified):
//   A[m=lane&15][k=quad*8+j], B[k=quad*8+j][n=lane&15], C: col=lane&15,row=quad*4+reg.

template <typename XT, int K, int XSTRIDE, int NOUT, int NOUT_PAD, int OSTRIDE>
__global__ __launch_bounds__(256) void gemm_mfma_kernel(const XT* __restrict__ X,
                                                        const float* __restrict__ W,
                                                        const float* __restrict__ dinv,
                                                        __half* __restrict__ Hs, int M) {
    constexpr int KCH = K / 32;
    constexpr int NT = NOUT_PAD / 16;
    constexpr int WPITCH = NOUT_PAD + 2;

    __shared__ _Float16 wh[K * WPITCH];
    __shared__ float sdinv[256];

    const int tid = threadIdx.x;
    const int bnode0 = blockIdx.x * 256;

    for (int i = tid; i < K * NOUT_PAD; i += 256) {
        int k = i / NOUT_PAD, n = i % NOUT_PAD;
        wh[k * WPITCH + n] = (n < NOUT) ? (_Float16)W[k * NOUT + n] : (_Float16)0.0f;
    }
    {
        int node = bnode0 + tid;
        sdinv[tid] = (node < M) ? dinv[node] : 0.f;
    }
    __syncthreads();

    const int wid = tid >> 6;
    const int lane = tid & 63;
    const int m = lane & 15;
    const int quad = lane >> 4;

    f16x8 bf[KCH][NT];
#pragma unroll
    for (int kc = 0; kc < KCH; ++kc)
#pragma unroll
        for (int nt = 0; nt < NT; ++nt)
#pragma unroll
            for (int j = 0; j < 8; ++j)
                bf[kc][nt][j] = wh[(kc * 32 + quad * 8 + j) * WPITCH + nt * 16 + m];

    for (int nt4 = 0; nt4 < 4; ++nt4) {
        const int nb = bnode0 + wid * 64 + nt4 * 16;
        if (nb >= M) break;
        const int rowi = min(nb + m, M - 1);
        const XT* xr = X + (size_t)rowi * XSTRIDE;

        f32x4 acc[NT];
#pragma unroll
        for (int nt = 0; nt < NT; ++nt) acc[nt] = (f32x4){0.f, 0.f, 0.f, 0.f};

#pragma unroll
        for (int kc = 0; kc < KCH; ++kc) {
            f16x8 af;
            if constexpr (std::is_same<XT, float>::value) {
                float4 u0 = *(const float4*)&xr[kc * 32 + quad * 8];
                float4 u1 = *(const float4*)&xr[kc * 32 + quad * 8 + 4];
                af[0] = (_Float16)u0.x;
                af[1] = (_Float16)u0.y;
                af[2] = (_Float16)u0.z;
                af[3] = (_Float16)u0.w;
                af[4] = (_Float16)u1.x;
                af[5] = (_Float16)u1.y;
                af[6] = (_Float16)u1.z;
                af[7] = (_Float16)u1.w;
            } else {
                af = *(const f16x8*)&xr[kc * 32 + quad * 8];
            }
#pragma unroll
            for (int nt = 0; nt < NT; ++nt)
                acc[nt] = __builtin_amdgcn_mfma_f32_16x16x32_f16(af, bf[kc][nt], acc[nt], 0, 0, 0);
        }

#pragma unroll
        for (int reg = 0; reg < 4; ++reg) {
            const int node = nb + quad * 4 + reg;
            if (node < M) {
                const float s = sdinv[node - bnode0];
#pragma unroll
                for (int nt = 0; nt < NT; ++nt) {
                    const int f = nt * 16 + m;
                    if (NOUT == NOUT_PAD || f < NOUT)
                        Hs[(size_t)node * OSTRIDE + f] = __float2half(acc[nt][reg] * s);
                }
            }
        }
    }
}

// ---------------- per-node wave gather, 8 row-slots x 8 chunk-lanes ----------------

__device__ inline void acc_row8(float (&acc)[8], uint4 u) {
    const __half2* hp = (const __half2*)&u;
#pragma unroll
    for (int k = 0; k < 4; ++k) {
        float2 f = __half22float2(hp[k]);
        acc[2 * k] += f.x;
        acc[2 * k + 1] += f.y;
    }
}

template <typename OutT, int FCHUNKS, int HSTRIDE, int OUTSTRIDE, bool RELU>
__global__ __launch_bounds__(256) void gather8_kernel(const int* __restrict__ rowptr,
                                                      const int* __restrict__ csr_src,
                                                      const float* __restrict__ dinv,
                                                      const __half* __restrict__ hs,
                                                      const float* __restrict__ b,
                                                      OutT* __restrict__ out, int n) {
    const int wave = (blockIdx.x * blockDim.x + threadIdx.x) >> 6;
    const int lane = threadIdx.x & 63;
    if (wave >= n) return;
    const int c = wave;
    const int g = lane >> 3;  // row slot
    const int q = lane & 7;   // 16B chunk within row
    const bool qv = q < FCHUNKS;

    const float dc = dinv[c];
    const int eBeg = rowptr[c];
    const int eEnd = rowptr[c + 1];

    float acc[8];
#pragma unroll
    for (int j = 0; j < 8; ++j) acc[j] = 0.f;

    if (g == 0 && qv) {
        uint4 u = *(const uint4*)&hs[(size_t)c * HSTRIDE + q * 8];
        acc_row8(acc, u);
    }

    for (int e = eBeg; e < eEnd; e += 16) {
        const int i0 = e + g;
        const int i1 = e + 8 + g;
        int r0 = (i0 < eEnd) ? csr_src[i0] : -1;
        int r1 = (i1 < eEnd) ? csr_src[i1] : -1;
        uint4 u0 = make_uint4(0, 0, 0, 0);
        uint4 u1 = make_uint4(0, 0, 0, 0);
        if (r0 >= 0 && qv) u0 = *(const uint4*)&hs[(size_t)r0 * HSTRIDE + q * 8];
        if (r1 >= 0 && qv) u1 = *(const uint4*)&hs[(size_t)r1 * HSTRIDE + q * 8];
        acc_row8(acc, u0);
        acc_row8(acc, u1);
    }

#pragma unroll
    for (int m = 8; m <= 32; m <<= 1)
#pragma unroll
        for (int j = 0; j < 8; ++j) acc[j] += __shfl_xor(acc[j], m, 64);

    if (g == 0 && qv) {
        float o[8];
#pragma unroll
        for (int j = 0; j < 8; ++j) {
            float v = fmaf(acc[j], dc, b[q * 8 + j]);
            o[j] = RELU ? fmaxf(v, 0.f) : v;
        }
        if constexpr (std::is_same<OutT, float>::value) {
            float* dst = &out[(size_t)c * OUTSTRIDE + q * 8];
            *(float4*)dst = make_float4(o[0], o[1], o[2], o[3]);
            *(float4*)(dst + 4) = make_float4(o[4], o[5], o[6], o[7]);
        } else {
            __half2 pk[4];
#pragma unroll
            for (int k = 0; k < 4; ++k) pk[k] = __floats2half2_rn(o[2 * k], o[2 * k + 1]);
            *(uint4*)&out[(size_t)c * OUTSTRIDE + q * 8] = *(uint4*)pk;
        }
    }
}

// ---------------- launch ----------------

extern "C" void kernel_launch(void* const* d_in, const int* in_sizes, int n_in,
                              void* d_out, int out_size, void* d_ws, size_t ws_size,
                              hipStream_t stream) {
    const float* x = (const float*)d_in[0];
    const int* row = (const int*)d_in[1];
    const int* col = row + N_EDGES;
    const float* W1 = (const float*)d_in[2];
    const float* b1 = (const float*)d_in[3];
    const float* W2 = (const float*)d_in[4];
    const float* b2 = (const float*)d_in[5];
    float* out = (float*)d_out;

    const int N = N_NODES, E = N_EDGES;

    // 256B-aligned workspace carve-up: h1s/agg1h rows must be 128B-aligned so a
    // random 128B row spans exactly 2 cache lines (16B alignment put them at
    // 48 mod 128 -> 3 lines -> +50% gather fetch).
    char* p = (char*)d_ws;
    auto alloc = [&](size_t bytes) {
        char* q = p;
        p += (bytes + 255) & ~(size_t)255;
        return q;
    };
    int* rowptr = (int*)alloc((size_t)(N + 1) * 4);
    int* csr_src = (int*)alloc((size_t)E * 4);
    int* gcursor = (int*)alloc((size_t)NBK * 4);
    unsigned* bke = (unsigned*)alloc((size_t)NBK * BCAP * 4);
    float* dinv = (float*)alloc((size_t)N * 4);
    __half* h1s = (__half*)alloc((size_t)N * HIDDEN * 2);     // stride 64 halves
    __half* agg1h = (__half*)alloc((size_t)N * HIDDEN * 2);   // fp16 agg, stride 64
    __half* h2s = (__half*)alloc((size_t)N * N_CLASSES * 2);  // packed stride 40 halves

    // CSR build: memset + 2 kernels
    hipMemsetAsync(gcursor, 0, (size_t)NBK * 4, stream);
    bucket_kernel<<<(E + CHUNK - 1) / CHUNK, 256, 0, stream>>>(row, col, gcursor, bke, E);
    place_kernel<<<NBK, 256, 0, stream>>>(gcursor, bke, rowptr, dinv, csr_src, N);

    // layer 1: fp32 X -> fp16 h1s (stride 64); gather -> fp16 agg1h
    gemm_mfma_kernel<float, N_FEAT, N_FEAT, HIDDEN, HIDDEN, HIDDEN>
        <<<(N + 255) / 256, 256, 0, stream>>>(x, W1, dinv, h1s, N);
    gather8_kernel<__half, 8, HIDDEN, HIDDEN, true>
        <<<(N + 3) / 4, 256, 0, stream>>>(rowptr, csr_src, dinv, h1s, b1, agg1h, N);

    // layer 2: fp16 agg1h -> packed h2s (stride 40); gather -> fp32 out
    gemm_mfma_kernel<_Float16, HIDDEN, HIDDEN, N_CLASSES, 48, N_CLASSES>
        <<<(N + 255) / 256, 256, 0, stream>>>((const _Float16*)agg1h, W2, dinv, h2s, N);
    gather8_kernel<float, 5, N_CLASSES, N_CLASSES, false>
        <<<(N + 3) / 4, 256, 0, stream>>>(rowptr, csr_src, dinv, h2s, b2, out, N);
}